// Round 5
// baseline (1841.686 us; speedup 1.0000x reference)
//
#include <hip/hip_runtime.h>

// Problem constants
// B=16, H=8, W=32, D=512, HID=512, C=7000, T=40 (41 scan steps)
#define NS 41
#define LSTM_NB 64

__device__ __forceinline__ float fsig(float x) { return 1.0f / (1.0f + __expf(-x)); }
__device__ __forceinline__ float ftanhf(float x) {
    float t = __expf(fminf(fmaxf(2.0f * x, -30.0f), 30.0f));
    return 1.0f - 2.0f / (t + 1.0f);
}

// ---------------------------------------------------------------------------
// Generic TN GEMM: C[m,n] = sum_k A[m,k]*B[n,k] (+bias[n]+bias2[n])
// ---------------------------------------------------------------------------
__launch_bounds__(256)
__global__ void gemm_tn(const float* __restrict__ A, const float* __restrict__ B,
                        float* __restrict__ C, int M, int N, int K,
                        int lda, int ldb, int ldc,
                        const float* __restrict__ bias, const float* __restrict__ bias2,
                        int cmode, int ksplit)
{
    __shared__ float As[32][68];
    __shared__ float Bs[32][68];
    const int tid = threadIdx.x;
    const int m0 = blockIdx.x * 64, n0 = blockIdx.y * 64;
    int ck = K, kb0 = 0;
    if (ksplit > 1) {
        ck = (((K + ksplit - 1) / ksplit) + 31) & ~31;
        kb0 = blockIdx.z * ck;
    }
    const int kend = min(K, kb0 + ck);
    float acc[4][4] = {};
    const int ty = tid >> 4, tx = tid & 15;

    for (int kb = kb0; kb < kend; kb += 32) {
#pragma unroll
        for (int j = 0; j < 2; ++j) {
            int i = tid + j * 256;
            int ml = i >> 3, kq = i & 7;
            int gm = m0 + ml, gk = kb + kq * 4;
            float4 v = make_float4(0.f, 0.f, 0.f, 0.f);
            if (gm < M) {
                if (gk + 4 <= kend) v = *(const float4*)(A + (size_t)gm * lda + gk);
                else {
                    float tmp[4] = {0.f, 0.f, 0.f, 0.f};
                    for (int e = 0; e < 4; ++e)
                        if (gk + e < kend) tmp[e] = A[(size_t)gm * lda + gk + e];
                    v = make_float4(tmp[0], tmp[1], tmp[2], tmp[3]);
                }
            }
            As[kq * 4 + 0][ml] = v.x; As[kq * 4 + 1][ml] = v.y;
            As[kq * 4 + 2][ml] = v.z; As[kq * 4 + 3][ml] = v.w;
        }
#pragma unroll
        for (int j = 0; j < 2; ++j) {
            int i = tid + j * 256;
            int nl = i >> 3, kq = i & 7;
            int gn = n0 + nl, gk = kb + kq * 4;
            float4 v = make_float4(0.f, 0.f, 0.f, 0.f);
            if (gn < N) {
                if (gk + 4 <= kend) v = *(const float4*)(B + (size_t)gn * ldb + gk);
                else {
                    float tmp[4] = {0.f, 0.f, 0.f, 0.f};
                    for (int e = 0; e < 4; ++e)
                        if (gk + e < kend) tmp[e] = B[(size_t)gn * ldb + gk + e];
                    v = make_float4(tmp[0], tmp[1], tmp[2], tmp[3]);
                }
            }
            Bs[kq * 4 + 0][nl] = v.x; Bs[kq * 4 + 1][nl] = v.y;
            Bs[kq * 4 + 2][nl] = v.z; Bs[kq * 4 + 3][nl] = v.w;
        }
        __syncthreads();
#pragma unroll
        for (int kk = 0; kk < 32; ++kk) {
            float4 a = *(const float4*)&As[kk][ty * 4];
            float4 bv = *(const float4*)&Bs[kk][tx * 4];
            float av[4] = {a.x, a.y, a.z, a.w};
            float bw[4] = {bv.x, bv.y, bv.z, bv.w};
#pragma unroll
            for (int i2 = 0; i2 < 4; ++i2)
#pragma unroll
                for (int j2 = 0; j2 < 4; ++j2)
                    acc[i2][j2] = fmaf(av[i2], bw[j2], acc[i2][j2]);
        }
        __syncthreads();
    }

#pragma unroll
    for (int i2 = 0; i2 < 4; ++i2) {
        int m = m0 + ty * 4 + i2;
        if (m >= M) continue;
#pragma unroll
        for (int j2 = 0; j2 < 4; ++j2) {
            int n = n0 + tx * 4 + j2;
            if (n >= N) continue;
            float v = acc[i2][j2];
            if (ksplit > 1) {
                atomicAdd(&C[(size_t)m * ldc + n], v);
            } else {
                if (bias)  v += bias[n];
                if (bias2) v += bias2[n];
                if (cmode == 2)
                    C[(size_t)(m & 15) * 280000 + (size_t)(m >> 4) * 7000 + n] = v;
                else
                    C[(size_t)m * ldc + n] = v;
            }
        }
    }
}

// ---------------------------------------------------------------------------
__launch_bounds__(256)
__global__ void build_xs(const float* __restrict__ hw, const float* __restrict__ xs_tf,
                         const float* __restrict__ w_lin1, const float* __restrict__ b_lin1,
                         float* __restrict__ xs)
{
    int blk = blockIdx.x;
    int t = blk >> 4, b = blk & 15;
    for (int h = threadIdx.x; h < 512; h += 256) {
        float v;
        if (t == 0)      v = hw[b * 512 + h];
        else if (t == 1) v = w_lin1[(size_t)h * 7000 + 6997] + b_lin1[h];
        else             v = xs_tf[((size_t)b * 39 + (t - 2)) * 512 + h] + b_lin1[h];
        xs[((size_t)t * 16 + b) * 512 + h] = v;
    }
}

// ---------------------------------------------------------------------------
__launch_bounds__(256)
__global__ void conv3x3(const float* __restrict__ V, const float* __restrict__ w2,
                        const float* __restrict__ b2, float* __restrict__ outc)
{
    const int b = blockIdx.y, d0 = blockIdx.x * 8;
    const int tid = threadIdx.x;
    const int h = tid >> 5, w = tid & 31;
    __shared__ float Vs[256];
    float acc[8] = {0.f, 0.f, 0.f, 0.f, 0.f, 0.f, 0.f, 0.f};
    const float* Vb = V + (size_t)b * 512 * 256;
    for (int c = 0; c < 512; ++c) {
        __syncthreads();
        Vs[tid] = Vb[(size_t)c * 256 + tid];
        __syncthreads();
        float v[9];
#pragma unroll
        for (int dh = 0; dh < 3; ++dh)
#pragma unroll
            for (int dw = 0; dw < 3; ++dw) {
                int hh = h + dh - 1, ww = w + dw - 1;
                v[dh * 3 + dw] = (hh >= 0 && hh < 8 && ww >= 0 && ww < 32) ? Vs[hh * 32 + ww] : 0.f;
            }
#pragma unroll
        for (int dl = 0; dl < 8; ++dl) {
            const float* wp = w2 + ((size_t)(d0 + dl) * 512 + c) * 9;
            float a = acc[dl];
            a = fmaf(v[0], wp[0], a); a = fmaf(v[1], wp[1], a); a = fmaf(v[2], wp[2], a);
            a = fmaf(v[3], wp[3], a); a = fmaf(v[4], wp[4], a); a = fmaf(v[5], wp[5], a);
            a = fmaf(v[6], wp[6], a); a = fmaf(v[7], wp[7], a); a = fmaf(v[8], wp[8], a);
            acc[dl] = a;
        }
    }
#pragma unroll
    for (int dl = 0; dl < 8; ++dl)
        outc[((size_t)b * 512 + d0 + dl) * 256 + tid] = acc[dl] + b2[d0 + dl];
}

// ---------------------------------------------------------------------------
// Contention-free grid barrier: every line has exactly ONE poller.
//  - spinner bk: store phase to its own flag line; poll its OWN release line.
//  - master (block 0, wave 0): lane i polls flag line i; after the wave
//    reconverges (all lanes' loops exited => all blocks arrived), each lane
//    stores the phase to release line i.
// Monotonic phases, agent-scope relaxed atomics only (no L2 flush).
// h-data coherence: agent-scope write-through stores + fresh slot per step.
// ---------------------------------------------------------------------------
__device__ __forceinline__ void gbar3(unsigned* __restrict__ flags,
                                      unsigned* __restrict__ rel,
                                      unsigned ph)
{
    __syncthreads();   // all waves done; vmcnt(0) -> h stores acked
    if (blockIdx.x == 0) {
        if (threadIdx.x < 64) {
            if (threadIdx.x > 0) {
                while (__hip_atomic_load(&flags[threadIdx.x * 32],
                                         __ATOMIC_RELAXED, __HIP_MEMORY_SCOPE_AGENT) < ph)
                    __builtin_amdgcn_s_sleep(1);
            }
            // wave reconverged: every block has arrived
            __hip_atomic_store(&rel[threadIdx.x * 32], ph,
                               __ATOMIC_RELAXED, __HIP_MEMORY_SCOPE_AGENT);
        }
    } else {
        if (threadIdx.x == 0) {
            __hip_atomic_store(&flags[blockIdx.x * 32], ph,
                               __ATOMIC_RELAXED, __HIP_MEMORY_SCOPE_AGENT);
            while (__hip_atomic_load(&rel[blockIdx.x * 32],
                                     __ATOMIC_RELAXED, __HIP_MEMORY_SCOPE_AGENT) < ph)
                __builtin_amdgcn_s_sleep(1);
        }
    }
    __syncthreads();
}

// LDS layout (floats): Hs1[16*516] Hs2[16*516] P1[1024] P2[1024] G1S[512]
//                      C1S[128] C2S[128]  -> 19328 floats = 77312 B (dynamic)
#define HS1_OFF 0
#define HS2_OFF 8256
#define P1_OFF  16512
#define P2_OFF  17536
#define G1S_OFF 18560
#define C1S_OFF 19072
#define C2S_OFF 19200
#define LSTM_LDS_FLOATS 19328

__launch_bounds__(1024, 1)
__global__ void lstm_rec(const float* __restrict__ g1x,
                         const float* __restrict__ Wih,
                         const float* __restrict__ Whh,
                         const float* __restrict__ bih,
                         const float* __restrict__ bhh,
                         float* __restrict__ h1all,   // 42 x 16 x 512
                         float* __restrict__ h2all,   // 42 x 16 x 512
                         unsigned* __restrict__ barflags)
{
    extern __shared__ float sh[];
    float* Hs1 = sh + HS1_OFF;
    float* Hs2 = sh + HS2_OFF;
    float* P1  = sh + P1_OFF;
    float* P2  = sh + P2_OFF;
    float* G1S = sh + G1S_OFF;
    float* C1S = sh + C1S_OFF;
    float* C2S = sh + C2S_OFF;

    const int bk = blockIdx.x;
    const int tid = threadIdx.x;
    const int p = tid & 511, half = tid >> 9;
    const int b = p & 15, ug = p >> 4;        // ug = u_l*4 + q
    const int u_l = ug >> 2, q = ug & 3;
    const int n = q * 512 + bk * 8 + u_l;
    const float4* wih4 = (const float4*)(Wih + (size_t)n * 512 + half * 256);
    const float4* whh4 = (const float4*)(Whh + (size_t)n * 512 + half * 256);
    const float4* hs1v = (const float4*)(Hs1 + b * 516 + half * 256);
    const float4* hs2v = (const float4*)(Hs2 + b * 516 + half * 256);
    unsigned* rel = barflags + 2048;

    // finisher constants (cell2 bias sums)
    float bs0 = 0.f, bs1 = 0.f, bs2 = 0.f, bs3 = 0.f;
    if (tid >= 128 && tid < 256) {
        int r = tid - 128, uuf = bk * 8 + (r >> 4);
        bs0 = bih[0 * 512 + uuf] + bhh[0 * 512 + uuf];
        bs1 = bih[1 * 512 + uuf] + bhh[1 * 512 + uuf];
        bs2 = bih[2 * 512 + uuf] + bhh[2 * 512 + uuf];
        bs3 = bih[3 * 512 + uuf] + bhh[3 * 512 + uuf];
    }
    if (tid < 128) { C1S[tid] = 0.f; C2S[tid] = 0.f; }

    // staging indices: 8 consecutive floats per thread
    const int e0 = tid * 8;
    const int sb = e0 >> 9, sj = e0 & 511;

    for (int k = 0; k <= NS; ++k) {           // 42 phases
        const bool doC1 = (k < NS);
        const bool doC2 = (k > 0);
        // ---- stage h (and g1x) into LDS
        {
            const float4* s1 = (const float4*)(h1all + (size_t)k * 8192 + e0);
            float4 a0 = s1[0], a1 = s1[1];
            *(float4*)(Hs1 + sb * 516 + sj) = a0;
            *(float4*)(Hs1 + sb * 516 + sj + 4) = a1;
            if (doC2) {
                const float4* s2 = (const float4*)(h2all + (size_t)(k - 1) * 8192 + e0);
                float4 b0 = s2[0], b1 = s2[1];
                *(float4*)(Hs2 + sb * 516 + sj) = b0;
                *(float4*)(Hs2 + sb * 516 + sj + 4) = b1;
            }
            if (doC1 && tid < 512)
                G1S[tid] = g1x[(size_t)(k * 16 + b) * 2048 + n];
        }
        __syncthreads();
        // ---- partial dots (2 threads per dot, split on K)
        if (doC1 && doC2) {
            float s1 = 0.f, s2a = 0.f, s2b = 0.f;
#pragma unroll 4
            for (int kk = 0; kk < 64; ++kk) {
                float4 wh = whh4[kk], wi = wih4[kk];
                float4 h1v = hs1v[kk], h2v = hs2v[kk];
                s1  = fmaf(wh.x, h1v.x, s1);  s1  = fmaf(wh.y, h1v.y, s1);
                s1  = fmaf(wh.z, h1v.z, s1);  s1  = fmaf(wh.w, h1v.w, s1);
                s2a = fmaf(wi.x, h1v.x, s2a); s2a = fmaf(wi.y, h1v.y, s2a);
                s2a = fmaf(wi.z, h1v.z, s2a); s2a = fmaf(wi.w, h1v.w, s2a);
                s2b = fmaf(wh.x, h2v.x, s2b); s2b = fmaf(wh.y, h2v.y, s2b);
                s2b = fmaf(wh.z, h2v.z, s2b); s2b = fmaf(wh.w, h2v.w, s2b);
            }
            P1[tid] = s1; P2[tid] = s2a + s2b;
        } else if (doC1) {
            float s1 = 0.f;
#pragma unroll 8
            for (int kk = 0; kk < 64; ++kk) {
                float4 wh = whh4[kk], h1v = hs1v[kk];
                s1 = fmaf(wh.x, h1v.x, s1); s1 = fmaf(wh.y, h1v.y, s1);
                s1 = fmaf(wh.z, h1v.z, s1); s1 = fmaf(wh.w, h1v.w, s1);
            }
            P1[tid] = s1;
        } else {
            float s2a = 0.f, s2b = 0.f;
#pragma unroll 4
            for (int kk = 0; kk < 64; ++kk) {
                float4 wi = wih4[kk], wh = whh4[kk];
                float4 h1v = hs1v[kk], h2v = hs2v[kk];
                s2a = fmaf(wi.x, h1v.x, s2a); s2a = fmaf(wi.y, h1v.y, s2a);
                s2a = fmaf(wi.z, h1v.z, s2a); s2a = fmaf(wi.w, h1v.w, s2a);
                s2b = fmaf(wh.x, h2v.x, s2b); s2b = fmaf(wh.y, h2v.y, s2b);
                s2b = fmaf(wh.z, h2v.z, s2b); s2b = fmaf(wh.w, h2v.w, s2b);
            }
            P2[tid] = s2a + s2b;
        }
        __syncthreads();
        // ---- finish: cell1 on waves 0-1, cell2 on waves 2-3 (concurrent)
        if (tid < 128) {
            if (doC1) {
                int bb = tid & 15, uu = bk * 8 + (tid >> 4);
                int p0 = bb + 16 * ((tid >> 4) * 4);
                float gi = G1S[p0]      + P1[p0]      + P1[p0 + 512];
                float gf = G1S[p0 + 16] + P1[p0 + 16] + P1[p0 + 528];
                float gg = G1S[p0 + 32] + P1[p0 + 32] + P1[p0 + 544];
                float go = G1S[p0 + 48] + P1[p0 + 48] + P1[p0 + 560];
                float cn = fsig(gf) * C1S[tid] + fsig(gi) * ftanhf(gg);
                C1S[tid] = cn;
                __hip_atomic_store(&h1all[(size_t)(k + 1) * 8192 + bb * 512 + uu],
                                   fsig(go) * ftanhf(cn),
                                   __ATOMIC_RELAXED, __HIP_MEMORY_SCOPE_AGENT);
            }
        } else if (tid < 256) {
            if (doC2) {
                int r = tid - 128;
                int bb = r & 15, uu = bk * 8 + (r >> 4);
                int p0 = bb + 16 * ((r >> 4) * 4);
                float gi = bs0 + P2[p0]      + P2[p0 + 512];
                float gf = bs1 + P2[p0 + 16] + P2[p0 + 528];
                float gg = bs2 + P2[p0 + 32] + P2[p0 + 544];
                float go = bs3 + P2[p0 + 48] + P2[p0 + 560];
                float cn = fsig(gf) * C2S[r] + fsig(gi) * ftanhf(gg);
                C2S[r] = cn;
                __hip_atomic_store(&h2all[(size_t)k * 8192 + bb * 512 + uu],
                                   fsig(go) * ftanhf(cn),
                                   __ATOMIC_RELAXED, __HIP_MEMORY_SCOPE_AGENT);
            }
        }
        gbar3(barflags, rel, (unsigned)(k + 1));
    }
}

// ---------------------------------------------------------------------------
// Attention, 4 timesteps per block: share conv2V and V reads across 4 to's.
// grid = 160 (blk = grp*16 + b, grp 0..9 covering to = 4*grp..4*grp+3)
// ---------------------------------------------------------------------------
#define TO_PER 4
__launch_bounds__(256)
__global__ void attention_k(const float* __restrict__ conv2V, const float* __restrict__ hproj,
                            const float* __restrict__ V, const float* __restrict__ w3,
                            const float* __restrict__ b3, float* __restrict__ attw_out,
                            float* __restrict__ glimpse)
{
    const int blk = blockIdx.x;
    const int b = blk & 15, grp = blk >> 4;
    const int to0 = grp * TO_PER;
    const int tid = threadIdx.x;
    const float* cb = conv2V + (size_t)b * 512 * 256;
    __shared__ float hpS[TO_PER * 512];
    __shared__ float red[256];
    __shared__ float awS[TO_PER][256];
    for (int i = tid; i < TO_PER * 512; i += 256) {
        int t4 = i >> 9, d = i & 511;
        hpS[i] = hproj[((size_t)((to0 + t4) * 16 + b)) * 512 + d];
    }
    __syncthreads();
    float acc[TO_PER] = {0.f, 0.f, 0.f, 0.f};
    for (int d = 0; d < 512; ++d) {
        float x = cb[(size_t)d * 256 + tid];
        float wd = w3[d];
#pragma unroll
        for (int t4 = 0; t4 < TO_PER; ++t4)
            acc[t4] = fmaf(wd, ftanhf(x + hpS[t4 * 512 + d]), acc[t4]);
    }
    const float bb3 = b3[0];
#pragma unroll
    for (int t4 = 0; t4 < TO_PER; ++t4) {
        float logit = acc[t4] + bb3;
        red[tid] = logit; __syncthreads();
        for (int s = 128; s > 0; s >>= 1) { if (tid < s) red[tid] = fmaxf(red[tid], red[tid + s]); __syncthreads(); }
        float mx = red[0]; __syncthreads();
        float e = __expf(logit - mx);
        red[tid] = e; __syncthreads();
        for (int s = 128; s > 0; s >>= 1) { if (tid < s) red[tid] += red[tid + s]; __syncthreads(); }
        float aw = e / red[0];
        __syncthreads();
        awS[t4][tid] = aw;
        attw_out[(size_t)b * 10240 + (size_t)(to0 + t4) * 256 + tid] = aw;
    }
    __syncthreads();
    const float* Vb = V + (size_t)b * 512 * 256;
#pragma unroll
    for (int dl = 0; dl < 2; ++dl) {
        int d = tid + dl * 256;
        float g0 = 0.f, g1 = 0.f, g2 = 0.f, g3 = 0.f;
        for (int p4 = 0; p4 < 256; p4 += 4) {
            float4 vv = *(const float4*)(Vb + (size_t)d * 256 + p4);
            g0 = fmaf(vv.x, awS[0][p4], g0); g0 = fmaf(vv.y, awS[0][p4+1], g0);
            g0 = fmaf(vv.z, awS[0][p4+2], g0); g0 = fmaf(vv.w, awS[0][p4+3], g0);
            g1 = fmaf(vv.x, awS[1][p4], g1); g1 = fmaf(vv.y, awS[1][p4+1], g1);
            g1 = fmaf(vv.z, awS[1][p4+2], g1); g1 = fmaf(vv.w, awS[1][p4+3], g1);
            g2 = fmaf(vv.x, awS[2][p4], g2); g2 = fmaf(vv.y, awS[2][p4+1], g2);
            g2 = fmaf(vv.z, awS[2][p4+2], g2); g2 = fmaf(vv.w, awS[2][p4+3], g2);
            g3 = fmaf(vv.x, awS[3][p4], g3); g3 = fmaf(vv.y, awS[3][p4+1], g3);
            g3 = fmaf(vv.z, awS[3][p4+2], g3); g3 = fmaf(vv.w, awS[3][p4+3], g3);
        }
        glimpse[((size_t)((to0 + 0) * 16 + b)) * 512 + d] = g0;
        glimpse[((size_t)((to0 + 1) * 16 + b)) * 512 + d] = g1;
        glimpse[((size_t)((to0 + 2) * 16 + b)) * 512 + d] = g2;
        glimpse[((size_t)((to0 + 3) * 16 + b)) * 512 + d] = g3;
    }
}

// feat[r][k] = k<512 ? h2all[r+32][k] : glimpse[r][k-512];  grid = 2560
__launch_bounds__(256)
__global__ void concat_feat(const float* __restrict__ h2all, const float* __restrict__ glimpse,
                            float* __restrict__ feat)
{
    int idx = blockIdx.x * 256 + threadIdx.x;
    int r = idx >> 10, k = idx & 1023;
    feat[idx] = (k < 512) ? h2all[(size_t)(r + 32) * 512 + k]
                          : glimpse[(size_t)r * 512 + (k - 512)];
}

// In-place log_softmax over rows of 7000 in the final output. grid = 640
__launch_bounds__(256)
__global__ void logsoftmax_k(float* __restrict__ out)
{
    int r = blockIdx.x;
    int b = r & 15, to = r >> 4;
    float* row = out + (size_t)b * 280000 + (size_t)to * 7000;
    __shared__ float buf[7000];
    __shared__ float red[256];
    int tid = threadIdx.x;
    float mx = -1e30f;
    for (int i = tid; i < 7000; i += 256) { float v = row[i]; buf[i] = v; mx = fmaxf(mx, v); }
    red[tid] = mx; __syncthreads();
    for (int s = 128; s > 0; s >>= 1) { if (tid < s) red[tid] = fmaxf(red[tid], red[tid + s]); __syncthreads(); }
    mx = red[0]; __syncthreads();
    float sm = 0.f;
    for (int i = tid; i < 7000; i += 256) sm += __expf(buf[i] - mx);
    red[tid] = sm; __syncthreads();
    for (int s = 128; s > 0; s >>= 1) { if (tid < s) red[tid] += red[tid + s]; __syncthreads(); }
    float lse = mx + __logf(red[0]);
    for (int i = tid; i < 7000; i += 256) row[i] = buf[i] - lse;
}

// ---------------------------------------------------------------------------
extern "C" void kernel_launch(void* const* d_in, const int* in_sizes, int n_in,
                              void* d_out, int out_size, void* d_ws, size_t ws_size,
                              hipStream_t stream)
{
    const float* hw      = (const float*)d_in[0];
    const float* y       = (const float*)d_in[1];
    const float* V       = (const float*)d_in[2];
    const float* w_lin1  = (const float*)d_in[3];
    const float* b_lin1  = (const float*)d_in[4];
    const float* W_ih    = (const float*)d_in[5];
    const float* b_ih    = (const float*)d_in[6];
    const float* W_hh    = (const float*)d_in[7];
    const float* b_hh    = (const float*)d_in[8];
    const float* w_conv1 = (const float*)d_in[9];
    const float* b_conv1 = (const float*)d_in[10];
    const float* w_conv2 = (const float*)d_in[11];
    const float* b_conv2 = (const float*)d_in[12];
    const float* w_conv3 = (const float*)d_in[13];
    const float* b_conv3 = (const float*)d_in[14];
    const float* w_lin2  = (const float*)d_in[15];
    const float* b_lin2  = (const float*)d_in[16];
    float* out = (float*)d_out;

    float* ws = (float*)d_ws;
    float* xs_tf   = ws + 0;                        // 319488
    unsigned* barflags = (unsigned*)(ws + 319488);  // 4096 uints: flags[2048] rel[2048]
    float* h1all   = ws + 323584;                   // 42*8192 = 344064
    float* h2all   = ws + 667648;                   // 344064
    float* xs      = ws + 1011712;                  // 335872
    float* g1x     = ws + 1347584;                  // 1343488
    float* conv2V  = ws + 2691072;                  // 2097152
    float* hproj   = ws + 4788224;                  // 327680
    float* glimpse = ws + 5115904;                  // 327680
    float* feat    = ws + 5443584;                  // 655360 -> end 6098944

    // zero: xs_tf + barflags + h1all slot0 ; h2all slot0
    hipMemsetAsync(ws, 0, (size_t)331776 * sizeof(float), stream);
    hipMemsetAsync(ws + 667648, 0, (size_t)8192 * sizeof(float), stream);

    // xs_tf = y @ w_lin1^T   (624 x 512, K=7000, split-K=8)
    gemm_tn<<<dim3(10, 8, 8), 256, 0, stream>>>(y, w_lin1, xs_tf, 624, 512, 7000,
                                                7000, 7000, 512, nullptr, nullptr, 0, 8);
    build_xs<<<656, 256, 0, stream>>>(hw, xs_tf, w_lin1, b_lin1, xs);
    // g1x = xs @ W_ih^T + b_ih + b_hh   (656 x 2048, K=512)
    gemm_tn<<<dim3(11, 32, 1), 256, 0, stream>>>(xs, W_ih, g1x, 656, 2048, 512,
                                                 512, 512, 2048, b_ih, b_hh, 0, 1);
    conv3x3<<<dim3(64, 16), 256, 0, stream>>>(V, w_conv2, b_conv2, conv2V);

    // sequential recurrence (cooperative, 42 pipelined phases, dynamic LDS)
    static bool attr_set = false;
    if (!attr_set) {
        hipFuncSetAttribute((const void*)lstm_rec,
                            hipFuncAttributeMaxDynamicSharedMemorySize,
                            LSTM_LDS_FLOATS * 4);
        attr_set = true;
    }
    void* args[] = {(void*)&g1x, (void*)&W_ih, (void*)&W_hh, (void*)&b_ih, (void*)&b_hh,
                    (void*)&h1all, (void*)&h2all, (void*)&barflags};
    hipLaunchCooperativeKernel((void*)lstm_rec, dim3(LSTM_NB), dim3(1024), args,
                               LSTM_LDS_FLOATS * 4, stream);

    // hproj = h2[steps 1..40] @ w1^T + b_conv1   (640 x 512, K=512)
    gemm_tn<<<dim3(10, 8, 1), 256, 0, stream>>>(h2all + 2 * 8192, w_conv1, hproj,
                                                640, 512, 512, 512, 512, 512,
                                                b_conv1, nullptr, 0, 1);
    attention_k<<<160, 256, 0, stream>>>(conv2V, hproj, V, w_conv3, b_conv3,
                                         out + 4480000, glimpse);
    concat_feat<<<2560, 256, 0, stream>>>(h2all, glimpse, feat);
    gemm_tn<<<dim3(10, 110, 1), 256, 0, stream>>>(feat, w_lin2, out, 640, 7000, 1024,
                                                  1024, 1024, 7000, b_lin2, nullptr, 2, 1);
    logsoftmax_k<<<640, 256, 0, stream>>>(out);
}

// Round 6
// 1168.498 us; speedup vs baseline: 1.5761x; 1.5761x over previous
//
#include <hip/hip_runtime.h>

// Problem constants: B=16, H=8, W=32, D=512, HID=512, C=7000, T=40 (41 steps)
#define NS 41
#define LSTM_NB 64

typedef _Float16 f16x8 __attribute__((ext_vector_type(8)));
typedef float f32x4 __attribute__((ext_vector_type(4)));
typedef unsigned short ushort_t;

__device__ __forceinline__ float fsig(float x) { return 1.0f / (1.0f + __expf(-x)); }
__device__ __forceinline__ float ftanhf(float x) {
    float t = __expf(fminf(fmaxf(2.0f * x, -30.0f), 30.0f));
    return 1.0f - 2.0f / (t + 1.0f);
}

// ---------------------------------------------------------------------------
// Generic TN GEMM: C[m,n] = sum_k A[m,k]*B[n,k] (+bias[n]+bias2[n])
// ---------------------------------------------------------------------------
__launch_bounds__(256)
__global__ void gemm_tn(const float* __restrict__ A, const float* __restrict__ B,
                        float* __restrict__ C, int M, int N, int K,
                        int lda, int ldb, int ldc,
                        const float* __restrict__ bias, const float* __restrict__ bias2,
                        int cmode, int ksplit)
{
    __shared__ float As[32][68];
    __shared__ float Bs[32][68];
    const int tid = threadIdx.x;
    const int m0 = blockIdx.x * 64, n0 = blockIdx.y * 64;
    int ck = K, kb0 = 0;
    if (ksplit > 1) {
        ck = (((K + ksplit - 1) / ksplit) + 31) & ~31;
        kb0 = blockIdx.z * ck;
    }
    const int kend = min(K, kb0 + ck);
    float acc[4][4] = {};
    const int ty = tid >> 4, tx = tid & 15;

    for (int kb = kb0; kb < kend; kb += 32) {
#pragma unroll
        for (int j = 0; j < 2; ++j) {
            int i = tid + j * 256;
            int ml = i >> 3, kq = i & 7;
            int gm = m0 + ml, gk = kb + kq * 4;
            float4 v = make_float4(0.f, 0.f, 0.f, 0.f);
            if (gm < M) {
                if (gk + 4 <= kend) v = *(const float4*)(A + (size_t)gm * lda + gk);
                else {
                    float tmp[4] = {0.f, 0.f, 0.f, 0.f};
                    for (int e = 0; e < 4; ++e)
                        if (gk + e < kend) tmp[e] = A[(size_t)gm * lda + gk + e];
                    v = make_float4(tmp[0], tmp[1], tmp[2], tmp[3]);
                }
            }
            As[kq * 4 + 0][ml] = v.x; As[kq * 4 + 1][ml] = v.y;
            As[kq * 4 + 2][ml] = v.z; As[kq * 4 + 3][ml] = v.w;
        }
#pragma unroll
        for (int j = 0; j < 2; ++j) {
            int i = tid + j * 256;
            int nl = i >> 3, kq = i & 7;
            int gn = n0 + nl, gk = kb + kq * 4;
            float4 v = make_float4(0.f, 0.f, 0.f, 0.f);
            if (gn < N) {
                if (gk + 4 <= kend) v = *(const float4*)(B + (size_t)gn * ldb + gk);
                else {
                    float tmp[4] = {0.f, 0.f, 0.f, 0.f};
                    for (int e = 0; e < 4; ++e)
                        if (gk + e < kend) tmp[e] = B[(size_t)gn * ldb + gk + e];
                    v = make_float4(tmp[0], tmp[1], tmp[2], tmp[3]);
                }
            }
            Bs[kq * 4 + 0][nl] = v.x; Bs[kq * 4 + 1][nl] = v.y;
            Bs[kq * 4 + 2][nl] = v.z; Bs[kq * 4 + 3][nl] = v.w;
        }
        __syncthreads();
#pragma unroll
        for (int kk = 0; kk < 32; ++kk) {
            float4 a = *(const float4*)&As[kk][ty * 4];
            float4 bv = *(const float4*)&Bs[kk][tx * 4];
            float av[4] = {a.x, a.y, a.z, a.w};
            float bw[4] = {bv.x, bv.y, bv.z, bv.w};
#pragma unroll
            for (int i2 = 0; i2 < 4; ++i2)
#pragma unroll
                for (int j2 = 0; j2 < 4; ++j2)
                    acc[i2][j2] = fmaf(av[i2], bw[j2], acc[i2][j2]);
        }
        __syncthreads();
    }

#pragma unroll
    for (int i2 = 0; i2 < 4; ++i2) {
        int m = m0 + ty * 4 + i2;
        if (m >= M) continue;
#pragma unroll
        for (int j2 = 0; j2 < 4; ++j2) {
            int n = n0 + tx * 4 + j2;
            if (n >= N) continue;
            float v = acc[i2][j2];
            if (ksplit > 1) {
                atomicAdd(&C[(size_t)m * ldc + n], v);
            } else {
                if (bias)  v += bias[n];
                if (bias2) v += bias2[n];
                if (cmode == 2)
                    C[(size_t)(m & 15) * 280000 + (size_t)(m >> 4) * 7000 + n] = v;
                else
                    C[(size_t)m * ldc + n] = v;
            }
        }
    }
}

// ---------------------------------------------------------------------------
__launch_bounds__(256)
__global__ void build_xs(const float* __restrict__ hw, const float* __restrict__ xs_tf,
                         const float* __restrict__ w_lin1, const float* __restrict__ b_lin1,
                         float* __restrict__ xs)
{
    int blk = blockIdx.x;
    int t = blk >> 4, b = blk & 15;
    for (int h = threadIdx.x; h < 512; h += 256) {
        float v;
        if (t == 0)      v = hw[b * 512 + h];
        else if (t == 1) v = w_lin1[(size_t)h * 7000 + 6997] + b_lin1[h];
        else             v = xs_tf[((size_t)b * 39 + (t - 2)) * 512 + h] + b_lin1[h];
        xs[((size_t)t * 16 + b) * 512 + h] = v;
    }
}

// ---------------------------------------------------------------------------
__launch_bounds__(256)
__global__ void conv3x3(const float* __restrict__ V, const float* __restrict__ w2,
                        const float* __restrict__ b2, float* __restrict__ outc)
{
    const int b = blockIdx.y, d0 = blockIdx.x * 8;
    const int tid = threadIdx.x;
    const int h = tid >> 5, w = tid & 31;
    __shared__ float Vs[256];
    float acc[8] = {0.f, 0.f, 0.f, 0.f, 0.f, 0.f, 0.f, 0.f};
    const float* Vb = V + (size_t)b * 512 * 256;
    for (int c = 0; c < 512; ++c) {
        __syncthreads();
        Vs[tid] = Vb[(size_t)c * 256 + tid];
        __syncthreads();
        float v[9];
#pragma unroll
        for (int dh = 0; dh < 3; ++dh)
#pragma unroll
            for (int dw = 0; dw < 3; ++dw) {
                int hh = h + dh - 1, ww = w + dw - 1;
                v[dh * 3 + dw] = (hh >= 0 && hh < 8 && ww >= 0 && ww < 32) ? Vs[hh * 32 + ww] : 0.f;
            }
#pragma unroll
        for (int dl = 0; dl < 8; ++dl) {
            const float* wp = w2 + ((size_t)(d0 + dl) * 512 + c) * 9;
            float a = acc[dl];
            a = fmaf(v[0], wp[0], a); a = fmaf(v[1], wp[1], a); a = fmaf(v[2], wp[2], a);
            a = fmaf(v[3], wp[3], a); a = fmaf(v[4], wp[4], a); a = fmaf(v[5], wp[5], a);
            a = fmaf(v[6], wp[6], a); a = fmaf(v[7], wp[7], a); a = fmaf(v[8], wp[8], a);
            acc[dl] = a;
        }
    }
#pragma unroll
    for (int dl = 0; dl < 8; ++dl)
        outc[((size_t)b * 512 + d0 + dl) * 256 + tid] = acc[dl] + b2[d0 + dl];
}

// ---------------------------------------------------------------------------
// Weight prep: swizzle Wih/Whh (f32 [2048][512]) into per-wave MFMA A-fragment
// layout, f16. tile = mat*2048 + bk*32 + rt*16 + ks ; within tile lane l holds
// W[row = q*512 + bk*8 + u_l][k = ks*32 + (l>>4)*8 + j], j=0..7, where
// block-local row r = rt*16 + (l&15), q = r>>3, u_l = r&7.
// ---------------------------------------------------------------------------
__launch_bounds__(64)
__global__ void wprep_k(const float* __restrict__ Wih, const float* __restrict__ Whh,
                        ushort_t* __restrict__ wprep)
{
    const int tile = blockIdx.x;
    const int l = threadIdx.x;
    const int ks = tile & 15, rt = (tile >> 4) & 1, bk = (tile >> 5) & 63, mat = tile >> 11;
    const int r = rt * 16 + (l & 15);
    const int row = (r >> 3) * 512 + bk * 8 + (r & 7);
    const int k0 = ks * 32 + (l >> 4) * 8;
    const float* src = (mat ? Whh : Wih) + (size_t)row * 512 + k0;
    ushort_t* dst = wprep + ((size_t)tile * 64 + l) * 8;
#pragma unroll
    for (int j = 0; j < 8; ++j) {
        _Float16 v = (_Float16)src[j];
        dst[j] = __builtin_bit_cast(ushort_t, v);
    }
}

// ---------------------------------------------------------------------------
// Contention-free grid barrier (r5 gbar3, kept)
// ---------------------------------------------------------------------------
__device__ __forceinline__ void gbar3(unsigned* __restrict__ flags,
                                      unsigned* __restrict__ rel,
                                      unsigned ph)
{
    __syncthreads();
    if (blockIdx.x == 0) {
        if (threadIdx.x < 64) {
            if (threadIdx.x > 0) {
                while (__hip_atomic_load(&flags[threadIdx.x * 32],
                                         __ATOMIC_RELAXED, __HIP_MEMORY_SCOPE_AGENT) < ph)
                    __builtin_amdgcn_s_sleep(1);
            }
            __hip_atomic_store(&rel[threadIdx.x * 32], ph,
                               __ATOMIC_RELAXED, __HIP_MEMORY_SCOPE_AGENT);
        }
    } else {
        if (threadIdx.x == 0) {
            __hip_atomic_store(&flags[blockIdx.x * 32], ph,
                               __ATOMIC_RELAXED, __HIP_MEMORY_SCOPE_AGENT);
            while (__hip_atomic_load(&rel[blockIdx.x * 32],
                                     __ATOMIC_RELAXED, __HIP_MEMORY_SCOPE_AGENT) < ph)
                __builtin_amdgcn_s_sleep(1);
        }
    }
    __syncthreads();
}

// ---------------------------------------------------------------------------
// MFMA LSTM recurrence. 64 blocks x 512 threads. Block bk owns units
// [8bk,8bk+8) (32 gate rows). Phase k: stage h1[k],h2[k-1] (f16) + g1x into
// LDS; waves 0-5 compute P1=Whh*h1, P2a=Wih*h1, P2b=Whh*h2 via
// mfma_f32_16x16x32_f16 (wave w: product p=w>>1, row-tile rt=w&1, full K);
// finish: 128 threads apply gate nonlinearity, store h f16 (agent, packed
// uint) + h2 f32 (plain, for downstream). One barrier per phase.
// ---------------------------------------------------------------------------
__launch_bounds__(512, 1)
__global__ void lstm_rec(const float* __restrict__ g1x,
                         const ushort_t* __restrict__ wprep,
                         const float* __restrict__ bih,
                         const float* __restrict__ bhh,
                         ushort_t* __restrict__ h1h,   // 42 x 16 x 512 f16
                         ushort_t* __restrict__ h2h,   // 42 x 16 x 512 f16
                         float* __restrict__ h2f,      // 42 x 16 x 512 f32
                         unsigned* __restrict__ barflags)
{
    __shared__ _Float16 Hs1[16 * 520];
    __shared__ _Float16 Hs2[16 * 520];
    __shared__ float G1S[512];
    __shared__ float Dlds[3][32 * 17];
    __shared__ float C1S[128];
    __shared__ float C2S[128];

    const int bk = blockIdx.x;
    const int tid = threadIdx.x;
    const int w = tid >> 6, lane = tid & 63;
    unsigned* rel = barflags + 2048;

    if (tid < 128) { C1S[tid] = 0.f; C2S[tid] = 0.f; }

    // cell2 finisher bias sums: thread t2 = tid-64 handles (up = t2>>4, bb)
    float bs[4][2];
    if (tid >= 64 && tid < 128) {
        int up = (tid - 64) >> 4;
#pragma unroll
        for (int q = 0; q < 4; ++q)
#pragma unroll
            for (int j = 0; j < 2; ++j) {
                int u = bk * 8 + up * 2 + j;
                bs[q][j] = bih[q * 512 + u] + bhh[q * 512 + u];
            }
    }

    // mfma wave assignment
    const int p = w >> 1, rt = w & 1;          // valid for w<6
    const int mat = (p == 1) ? 0 : 1;          // P1,P2b use Whh(mat1); P2a uses Wih
    const ushort_t* wbase = wprep + (((size_t)(mat * 2048 + bk * 32 + rt * 16)) * 64 + lane) * 8;
    const int boff = (lane & 15) * 520 + (lane >> 4) * 8;
    const int drow0 = rt * 16 + (lane >> 4) * 4, dcol = lane & 15;

    for (int k = 0; k <= NS; ++k) {            // 42 phases
        const bool doC1 = (k < NS);
        const bool doC2 = (k > 0);
        // ---- stage into LDS
        {
#pragma unroll
            for (int j = 0; j < 2; ++j) {
                int idx = tid + j * 512;        // 1024 chunks of 16B
                int batch = idx >> 6, off = (idx & 63) * 8;
                uint4 v1 = *(const uint4*)(h1h + (size_t)k * 8192 + idx * 8);
                *(uint4*)(Hs1 + batch * 520 + off) = v1;
                if (doC2) {
                    uint4 v2 = *(const uint4*)(h2h + (size_t)(k - 1) * 8192 + idx * 8);
                    *(uint4*)(Hs2 + batch * 520 + off) = v2;
                }
            }
            if (doC1) {
                int r = tid >> 4, bb = tid & 15;
                int n = (r >> 3) * 512 + bk * 8 + (r & 7);
                G1S[tid] = g1x[(size_t)(k * 16 + bb) * 2048 + n];
            }
        }
        __syncthreads();
        // ---- MFMA: waves 0-5
        if (w < 6 && (p == 0 ? doC1 : doC2)) {
            const _Float16* hs = (p == 2) ? Hs2 : Hs1;
            f32x4 acc = {0.f, 0.f, 0.f, 0.f};
#pragma unroll
            for (int ks = 0; ks < 16; ++ks) {
                f16x8 a = *(const f16x8*)(wbase + (size_t)ks * 512);
                f16x8 b = *(const f16x8*)(hs + boff + ks * 32);
                acc = __builtin_amdgcn_mfma_f32_16x16x32_f16(a, b, acc, 0, 0, 0);
            }
#pragma unroll
            for (int r = 0; r < 4; ++r)
                Dlds[p][(drow0 + r) * 17 + dcol] = acc[r];
        }
        __syncthreads();
        // ---- finish
        if (tid < 64) {
            if (doC1) {
                int bb = tid & 15, up = tid >> 4;
                unsigned pk = 0;
#pragma unroll
                for (int j = 0; j < 2; ++j) {
                    int ul = up * 2 + j;
                    float gi = G1S[(0 * 8 + ul) * 16 + bb] + Dlds[0][(0 * 8 + ul) * 17 + bb];
                    float gf = G1S[(1 * 8 + ul) * 16 + bb] + Dlds[0][(1 * 8 + ul) * 17 + bb];
                    float gg = G1S[(2 * 8 + ul) * 16 + bb] + Dlds[0][(2 * 8 + ul) * 17 + bb];
                    float go = G1S[(3 * 8 + ul) * 16 + bb] + Dlds[0][(3 * 8 + ul) * 17 + bb];
                    float cn = fsig(gf) * C1S[bb * 8 + ul] + fsig(gi) * ftanhf(gg);
                    C1S[bb * 8 + ul] = cn;
                    _Float16 hv = (_Float16)(fsig(go) * ftanhf(cn));
                    pk |= (unsigned)__builtin_bit_cast(ushort_t, hv) << (16 * j);
                }
                unsigned* dst = (unsigned*)h1h;
                __hip_atomic_store(&dst[(size_t)((k + 1) * 16 + bb) * 256 + bk * 4 + up],
                                   pk, __ATOMIC_RELAXED, __HIP_MEMORY_SCOPE_AGENT);
            }
        } else if (tid < 128) {
            if (doC2) {
                int t2 = tid - 64;
                int bb = t2 & 15, up = t2 >> 4;
                unsigned pk = 0;
#pragma unroll
                for (int j = 0; j < 2; ++j) {
                    int ul = up * 2 + j;
                    float gi = bs[0][j] + Dlds[1][(0 * 8 + ul) * 17 + bb] + Dlds[2][(0 * 8 + ul) * 17 + bb];
                    float gf = bs[1][j] + Dlds[1][(1 * 8 + ul) * 17 + bb] + Dlds[2][(1 * 8 + ul) * 17 + bb];
                    float gg = bs[2][j] + Dlds[1][(2 * 8 + ul) * 17 + bb] + Dlds[2][(2 * 8 + ul) * 17 + bb];
                    float go = bs[3][j] + Dlds[1][(3 * 8 + ul) * 17 + bb] + Dlds[2][(3 * 8 + ul) * 17 + bb];
                    float cn = fsig(gf) * C2S[bb * 8 + ul] + fsig(gi) * ftanhf(gg);
                    C2S[bb * 8 + ul] = cn;
                    float hf = fsig(go) * ftanhf(cn);
                    h2f[(size_t)k * 8192 + bb * 512 + bk * 8 + ul] = hf;   // plain: cross-kernel only
                    _Float16 hv = (_Float16)hf;
                    pk |= (unsigned)__builtin_bit_cast(ushort_t, hv) << (16 * j);
                }
                unsigned* dst = (unsigned*)h2h;
                __hip_atomic_store(&dst[(size_t)(k * 16 + bb) * 256 + bk * 4 + up],
                                   pk, __ATOMIC_RELAXED, __HIP_MEMORY_SCOPE_AGENT);
            }
        }
        gbar3(barflags, rel, (unsigned)(k + 1));
    }
}

// ---------------------------------------------------------------------------
// Attention (r4 version, 640 blocks — r5's 160-block variant regressed)
// ---------------------------------------------------------------------------
__launch_bounds__(256)
__global__ void attention_k(const float* __restrict__ conv2V, const float* __restrict__ hproj,
                            const float* __restrict__ V, const float* __restrict__ w3,
                            const float* __restrict__ b3, float* __restrict__ attw_out,
                            float* __restrict__ glimpse)
{
    const int r = blockIdx.x;
    const int to = r >> 4, b = r & 15;
    const int tid = threadIdx.x;
    const float* cb = conv2V + (size_t)b * 512 * 256;
    const float* hp = hproj + (size_t)r * 512;
    __shared__ float red[256];
    float acc = 0.f;
#pragma unroll 4
    for (int d = 0; d < 512; ++d) {
        float x = cb[(size_t)d * 256 + tid] + hp[d];
        acc = fmaf(w3[d], ftanhf(x), acc);
    }
    float logit = acc + b3[0];
    red[tid] = logit; __syncthreads();
    for (int s = 128; s > 0; s >>= 1) { if (tid < s) red[tid] = fmaxf(red[tid], red[tid + s]); __syncthreads(); }
    float mx = red[0]; __syncthreads();
    float e = __expf(logit - mx);
    red[tid] = e; __syncthreads();
    for (int s = 128; s > 0; s >>= 1) { if (tid < s) red[tid] += red[tid + s]; __syncthreads(); }
    float aw = e / red[0];
    __syncthreads();
    attw_out[(size_t)b * 10240 + (size_t)to * 256 + tid] = aw;
    red[tid] = aw; __syncthreads();
    const float* Vb = V + (size_t)b * 512 * 256;
#pragma unroll
    for (int dl = 0; dl < 2; ++dl) {
        int d = tid + dl * 256;
        float g = 0.f;
        for (int p4 = 0; p4 < 256; p4 += 4) {
            float4 vv = *(const float4*)(Vb + (size_t)d * 256 + p4);
            g = fmaf(vv.x, red[p4], g);     g = fmaf(vv.y, red[p4 + 1], g);
            g = fmaf(vv.z, red[p4 + 2], g); g = fmaf(vv.w, red[p4 + 3], g);
        }
        glimpse[(size_t)r * 512 + d] = g;
    }
}

// feat[r][k] = k<512 ? h2f[r+32][k] : glimpse[r][k-512];  grid = 2560
__launch_bounds__(256)
__global__ void concat_feat(const float* __restrict__ h2f, const float* __restrict__ glimpse,
                            float* __restrict__ feat)
{
    int idx = blockIdx.x * 256 + threadIdx.x;
    int r = idx >> 10, k = idx & 1023;
    feat[idx] = (k < 512) ? h2f[(size_t)(r + 32) * 512 + k]
                          : glimpse[(size_t)r * 512 + (k - 512)];
}

// In-place log_softmax over rows of 7000. grid = 640
__launch_bounds__(256)
__global__ void logsoftmax_k(float* __restrict__ out)
{
    int r = blockIdx.x;
    int b = r & 15, to = r >> 4;
    float* row = out + (size_t)b * 280000 + (size_t)to * 7000;
    __shared__ float buf[7000];
    __shared__ float red[256];
    int tid = threadIdx.x;
    float mx = -1e30f;
    for (int i = tid; i < 7000; i += 256) { float v = row[i]; buf[i] = v; mx = fmaxf(mx, v); }
    red[tid] = mx; __syncthreads();
    for (int s = 128; s > 0; s >>= 1) { if (tid < s) red[tid] = fmaxf(red[tid], red[tid + s]); __syncthreads(); }
    mx = red[0]; __syncthreads();
    float sm = 0.f;
    for (int i = tid; i < 7000; i += 256) sm += __expf(buf[i] - mx);
    red[tid] = sm; __syncthreads();
    for (int s = 128; s > 0; s >>= 1) { if (tid < s) red[tid] += red[tid + s]; __syncthreads(); }
    float lse = mx + __logf(red[0]);
    for (int i = tid; i < 7000; i += 256) row[i] = buf[i] - lse;
}

// ---------------------------------------------------------------------------
extern "C" void kernel_launch(void* const* d_in, const int* in_sizes, int n_in,
                              void* d_out, int out_size, void* d_ws, size_t ws_size,
                              hipStream_t stream)
{
    const float* hw      = (const float*)d_in[0];
    const float* y       = (const float*)d_in[1];
    const float* V       = (const float*)d_in[2];
    const float* w_lin1  = (const float*)d_in[3];
    const float* b_lin1  = (const float*)d_in[4];
    const float* W_ih    = (const float*)d_in[5];
    const float* b_ih    = (const float*)d_in[6];
    const float* W_hh    = (const float*)d_in[7];
    const float* b_hh    = (const float*)d_in[8];
    const float* w_conv1 = (const float*)d_in[9];
    const float* b_conv1 = (const float*)d_in[10];
    const float* w_conv2 = (const float*)d_in[11];
    const float* b_conv2 = (const float*)d_in[12];
    const float* w_conv3 = (const float*)d_in[13];
    const float* b_conv3 = (const float*)d_in[14];
    const float* w_lin2  = (const float*)d_in[15];
    const float* b_lin2  = (const float*)d_in[16];
    float* out = (float*)d_out;

    float* ws = (float*)d_ws;
    float* xs_tf   = ws + 0;                        // 319488
    unsigned* barflags = (unsigned*)(ws + 319488);  // 4096 uints: flags[2048] rel[2048]
    float* h2f     = ws + 323584;                   // 42*8192 = 344064 (f32, downstream)
    float* xs      = ws + 667648;                   // 335872
    float* g1x     = ws + 1003520;                  // 1343488
    float* conv2V  = ws + 2347008;                  // 2097152
    float* hproj   = ws + 4444160;                  // 327680
    float* glimpse = ws + 4771840;                  // 327680
    float* feat    = ws + 5099520;                  // 655360 -> 5754880
    // wprep (f16, 2*2048*512 = 4MB) aliases hproj/glimpse/feat (dead during lstm)
    ushort_t* wprep = (ushort_t*)(ws + 4444160);
    ushort_t* h1h  = (ushort_t*)(ws + 5754880);     // 42*8192 f16 = 86016 floats
    ushort_t* h2h  = (ushort_t*)(ws + 5840896);     // 86016 floats -> end 5926912

    // zero: xs_tf + barflags ; h1h slot0 ; h2h slot0
    hipMemsetAsync(ws, 0, (size_t)323584 * sizeof(float), stream);
    hipMemsetAsync(h1h, 0, 16384, stream);
    hipMemsetAsync(h2h, 0, 16384, stream);

    // xs_tf = y @ w_lin1^T   (624 x 512, K=7000, split-K=8)
    gemm_tn<<<dim3(10, 8, 8), 256, 0, stream>>>(y, w_lin1, xs_tf, 624, 512, 7000,
                                                7000, 7000, 512, nullptr, nullptr, 0, 8);
    build_xs<<<656, 256, 0, stream>>>(hw, xs_tf, w_lin1, b_lin1, xs);
    // g1x = xs @ W_ih^T + b_ih + b_hh   (656 x 2048, K=512)
    gemm_tn<<<dim3(11, 32, 1), 256, 0, stream>>>(xs, W_ih, g1x, 656, 2048, 512,
                                                 512, 512, 2048, b_ih, b_hh, 0, 1);
    conv3x3<<<dim3(64, 16), 256, 0, stream>>>(V, w_conv2, b_conv2, conv2V);
    // weight fragment prep (f16 swizzle)
    wprep_k<<<4096, 64, 0, stream>>>(W_ih, W_hh, wprep);

    // sequential recurrence (cooperative, 42 phases, MFMA gates)
    void* args[] = {(void*)&g1x, (void*)&wprep, (void*)&b_ih, (void*)&b_hh,
                    (void*)&h1h, (void*)&h2h, (void*)&h2f, (void*)&barflags};
    hipLaunchCooperativeKernel((void*)lstm_rec, dim3(LSTM_NB), dim3(512), args, 0, stream);

    // hproj = h2[steps 1..40] @ w1^T + b_conv1   (640 x 512, K=512)
    gemm_tn<<<dim3(10, 8, 1), 256, 0, stream>>>(h2f + 2 * 8192, w_conv1, hproj,
                                                640, 512, 512, 512, 512, 512,
                                                b_conv1, nullptr, 0, 1);
    attention_k<<<640, 256, 0, stream>>>(conv2V, hproj, V, w_conv3, b_conv3,
                                         out + 4480000, glimpse);
    concat_feat<<<2560, 256, 0, stream>>>(h2f, glimpse, feat);
    gemm_tn<<<dim3(10, 110, 1), 256, 0, stream>>>(feat, w_lin2, out, 640, 7000, 1024,
                                                  1024, 1024, 7000, b_lin2, nullptr, 2, 1);
    logsoftmax_k<<<640, 256, 0, stream>>>(out);
}

// Round 7
// 764.470 us; speedup vs baseline: 2.4091x; 1.5285x over previous
//
#include <hip/hip_runtime.h>

// Problem constants: B=16, H=8, W=32, D=512, HID=512, C=7000, T=40 (41 steps)
#define NS 41
#define LSTM_NB 64

typedef _Float16 f16x8 __attribute__((ext_vector_type(8)));
typedef float f32x4 __attribute__((ext_vector_type(4)));
typedef unsigned short ushort_t;

__device__ __forceinline__ float fsig(float x) { return 1.0f / (1.0f + __expf(-x)); }
__device__ __forceinline__ float ftanhf(float x) {
    float t = __expf(fminf(fmaxf(2.0f * x, -30.0f), 30.0f));
    return 1.0f - 2.0f / (t + 1.0f);
}

// ---------------------------------------------------------------------------
// Generic TN GEMM: C[m,n] = sum_k A[m,k]*B[n,k] (+bias[n]+bias2[n])
// ---------------------------------------------------------------------------
__launch_bounds__(256)
__global__ void gemm_tn(const float* __restrict__ A, const float* __restrict__ B,
                        float* __restrict__ C, int M, int N, int K,
                        int lda, int ldb, int ldc,
                        const float* __restrict__ bias, const float* __restrict__ bias2,
                        int cmode, int ksplit)
{
    __shared__ float As[32][68];
    __shared__ float Bs[32][68];
    const int tid = threadIdx.x;
    const int m0 = blockIdx.x * 64, n0 = blockIdx.y * 64;
    int ck = K, kb0 = 0;
    if (ksplit > 1) {
        ck = (((K + ksplit - 1) / ksplit) + 31) & ~31;
        kb0 = blockIdx.z * ck;
    }
    const int kend = min(K, kb0 + ck);
    float acc[4][4] = {};
    const int ty = tid >> 4, tx = tid & 15;

    for (int kb = kb0; kb < kend; kb += 32) {
#pragma unroll
        for (int j = 0; j < 2; ++j) {
            int i = tid + j * 256;
            int ml = i >> 3, kq = i & 7;
            int gm = m0 + ml, gk = kb + kq * 4;
            float4 v = make_float4(0.f, 0.f, 0.f, 0.f);
            if (gm < M) {
                if (gk + 4 <= kend) v = *(const float4*)(A + (size_t)gm * lda + gk);
                else {
                    float tmp[4] = {0.f, 0.f, 0.f, 0.f};
                    for (int e = 0; e < 4; ++e)
                        if (gk + e < kend) tmp[e] = A[(size_t)gm * lda + gk + e];
                    v = make_float4(tmp[0], tmp[1], tmp[2], tmp[3]);
                }
            }
            As[kq * 4 + 0][ml] = v.x; As[kq * 4 + 1][ml] = v.y;
            As[kq * 4 + 2][ml] = v.z; As[kq * 4 + 3][ml] = v.w;
        }
#pragma unroll
        for (int j = 0; j < 2; ++j) {
            int i = tid + j * 256;
            int nl = i >> 3, kq = i & 7;
            int gn = n0 + nl, gk = kb + kq * 4;
            float4 v = make_float4(0.f, 0.f, 0.f, 0.f);
            if (gn < N) {
                if (gk + 4 <= kend) v = *(const float4*)(B + (size_t)gn * ldb + gk);
                else {
                    float tmp[4] = {0.f, 0.f, 0.f, 0.f};
                    for (int e = 0; e < 4; ++e)
                        if (gk + e < kend) tmp[e] = B[(size_t)gn * ldb + gk + e];
                    v = make_float4(tmp[0], tmp[1], tmp[2], tmp[3]);
                }
            }
            Bs[kq * 4 + 0][nl] = v.x; Bs[kq * 4 + 1][nl] = v.y;
            Bs[kq * 4 + 2][nl] = v.z; Bs[kq * 4 + 3][nl] = v.w;
        }
        __syncthreads();
#pragma unroll
        for (int kk = 0; kk < 32; ++kk) {
            float4 a = *(const float4*)&As[kk][ty * 4];
            float4 bv = *(const float4*)&Bs[kk][tx * 4];
            float av[4] = {a.x, a.y, a.z, a.w};
            float bw[4] = {bv.x, bv.y, bv.z, bv.w};
#pragma unroll
            for (int i2 = 0; i2 < 4; ++i2)
#pragma unroll
                for (int j2 = 0; j2 < 4; ++j2)
                    acc[i2][j2] = fmaf(av[i2], bw[j2], acc[i2][j2]);
        }
        __syncthreads();
    }

#pragma unroll
    for (int i2 = 0; i2 < 4; ++i2) {
        int m = m0 + ty * 4 + i2;
        if (m >= M) continue;
#pragma unroll
        for (int j2 = 0; j2 < 4; ++j2) {
            int n = n0 + tx * 4 + j2;
            if (n >= N) continue;
            float v = acc[i2][j2];
            if (ksplit > 1) {
                atomicAdd(&C[(size_t)m * ldc + n], v);
            } else {
                if (bias)  v += bias[n];
                if (bias2) v += bias2[n];
                if (cmode == 2)
                    C[(size_t)(m & 15) * 280000 + (size_t)(m >> 4) * 7000 + n] = v;
                else
                    C[(size_t)m * ldc + n] = v;
            }
        }
    }
}

// ---------------------------------------------------------------------------
__launch_bounds__(256)
__global__ void build_xs(const float* __restrict__ hw, const float* __restrict__ xs_tf,
                         const float* __restrict__ w_lin1, const float* __restrict__ b_lin1,
                         float* __restrict__ xs)
{
    int blk = blockIdx.x;
    int t = blk >> 4, b = blk & 15;
    for (int h = threadIdx.x; h < 512; h += 256) {
        float v;
        if (t == 0)      v = hw[b * 512 + h];
        else if (t == 1) v = w_lin1[(size_t)h * 7000 + 6997] + b_lin1[h];
        else             v = xs_tf[((size_t)b * 39 + (t - 2)) * 512 + h] + b_lin1[h];
        xs[((size_t)t * 16 + b) * 512 + h] = v;
    }
}

// ---------------------------------------------------------------------------
// Conv weight prep: wconv[((dt2*9+tap)*16+kc)*64+lane][8] f16, A-fragment
// layout: lane holds w2[d = dt2*16 + (lane&15)][c = kc*32 + (lane>>4)*8 + j][tap]
// ---------------------------------------------------------------------------
__launch_bounds__(64)
__global__ void wconvprep_k(const float* __restrict__ w2, ushort_t* __restrict__ wconv)
{
    const int tile = blockIdx.x;              // 32*9*16 = 4608
    const int l = threadIdx.x;
    const int dt2 = tile / 144, rem = tile - dt2 * 144;
    const int tap = rem >> 4, kc = rem & 15;
    const int d = dt2 * 16 + (l & 15);
    const int c0 = kc * 32 + (l >> 4) * 8;
    ushort_t* dst = wconv + ((size_t)tile * 64 + l) * 8;
#pragma unroll
    for (int j = 0; j < 8; ++j) {
        _Float16 v = (_Float16)w2[((size_t)d * 512 + c0 + j) * 9 + tap];
        dst[j] = __builtin_bit_cast(ushort_t, v);
    }
}

// ---------------------------------------------------------------------------
// MFMA 3x3 conv. grid = 256 (b = blk>>4, dt = blk&15 -> d in [32dt,32dt+32)).
// LDS: zero-padded transposed plane Vpad[10*34 rows][32 c] f16 per 32-c chunk.
// Inner: 9 taps x 4 ntiles x 2 d-subtiles of mfma_f32_16x16x32_f16.
// Output f16 (+bias).
// ---------------------------------------------------------------------------
#define CROWS 340
__launch_bounds__(256)
__global__ void conv_mfma(const float* __restrict__ V, const ushort_t* __restrict__ wconv,
                          const float* __restrict__ b2, ushort_t* __restrict__ outh)
{
    __shared__ _Float16 Vt2[CROWS * 32];
    const int blk = blockIdx.x;
    const int b = blk >> 4, dt = blk & 15;
    const int tid = threadIdx.x;
    const int w = tid >> 6, lane = tid & 63;
    const int col = lane & 15, kg = lane >> 4;

    // zero border rows once
    for (int r = tid; r < CROWS; r += 256) {
        int hh = r / 34, ww = r - hh * 34;
        if (hh == 0 || hh == 9 || ww == 0 || ww == 33) {
            uint4 z = {0u, 0u, 0u, 0u};
            *(uint4*)&Vt2[r * 32]      = z;
            *(uint4*)&Vt2[r * 32 + 8]  = z;
            *(uint4*)&Vt2[r * 32 + 16] = z;
            *(uint4*)&Vt2[r * 32 + 24] = z;
        }
    }

    // per-lane LDS read bases (tap 0,0) for the 4 n-tiles this wave owns
    int rbase[4];
#pragma unroll
    for (int nt = 0; nt < 4; ++nt) {
        int n = (w * 4 + nt) * 16 + col;
        int hh = n >> 5, ww = n & 31;
        rbase[nt] = (hh * 34 + ww) * 32 + kg * 8;
    }

    const int cc = tid & 31, pg = tid >> 5;   // staging: channel cc, h-row pg
    f32x4 acc0[4] = {}, acc1[4] = {};

    for (int c0 = 0; c0 < 512; c0 += 32) {
        // stage V[b][c0+cc][pg*32 .. +32) -> Vt2[(pg+1)*34+1+w][cc]  (f16)
        const float* s = V + (((size_t)b * 512 + c0 + cc) * 256) + pg * 32;
        const int browbase = ((pg + 1) * 34 + 1) * 32 + cc;
#pragma unroll
        for (int j4 = 0; j4 < 8; ++j4) {
            float4 v4 = *(const float4*)(s + j4 * 4);
            Vt2[browbase + (j4 * 4 + 0) * 32] = (_Float16)v4.x;
            Vt2[browbase + (j4 * 4 + 1) * 32] = (_Float16)v4.y;
            Vt2[browbase + (j4 * 4 + 2) * 32] = (_Float16)v4.z;
            Vt2[browbase + (j4 * 4 + 3) * 32] = (_Float16)v4.w;
        }
        __syncthreads();
        const int kc = c0 >> 5;
#pragma unroll
        for (int tap = 0; tap < 9; ++tap) {
            const int kh = tap / 3, kw = tap - kh * 3;
            const int toff = (kh * 34 + kw) * 32;
            f16x8 a0 = *(const f16x8*)(wconv + ((((size_t)(dt * 2 + 0) * 9 + tap) * 16 + kc) * 64 + lane) * 8);
            f16x8 a1 = *(const f16x8*)(wconv + ((((size_t)(dt * 2 + 1) * 9 + tap) * 16 + kc) * 64 + lane) * 8);
#pragma unroll
            for (int nt = 0; nt < 4; ++nt) {
                f16x8 bf = *(const f16x8*)&Vt2[rbase[nt] + toff];
                acc0[nt] = __builtin_amdgcn_mfma_f32_16x16x32_f16(a0, bf, acc0[nt], 0, 0, 0);
                acc1[nt] = __builtin_amdgcn_mfma_f32_16x16x32_f16(a1, bf, acc1[nt], 0, 0, 0);
            }
        }
        __syncthreads();
    }

    // epilogue: d = dt*32 + sub*16 + kg*4 + r ; p = (w*4+nt)*16 + col
    float bv0[4], bv1[4];
#pragma unroll
    for (int r = 0; r < 4; ++r) {
        bv0[r] = b2[dt * 32 + kg * 4 + r];
        bv1[r] = b2[dt * 32 + 16 + kg * 4 + r];
    }
#pragma unroll
    for (int nt = 0; nt < 4; ++nt) {
        int p = (w * 4 + nt) * 16 + col;
#pragma unroll
        for (int r = 0; r < 4; ++r) {
            int d0 = dt * 32 + kg * 4 + r;
            int d1 = d0 + 16;
            _Float16 o0 = (_Float16)(acc0[nt][r] + bv0[r]);
            _Float16 o1 = (_Float16)(acc1[nt][r] + bv1[r]);
            outh[((size_t)b * 512 + d0) * 256 + p] = __builtin_bit_cast(ushort_t, o0);
            outh[((size_t)b * 512 + d1) * 256 + p] = __builtin_bit_cast(ushort_t, o1);
        }
    }
}

// ---------------------------------------------------------------------------
// LSTM weight prep (unchanged from r6)
// ---------------------------------------------------------------------------
__launch_bounds__(64)
__global__ void wprep_k(const float* __restrict__ Wih, const float* __restrict__ Whh,
                        ushort_t* __restrict__ wprep)
{
    const int tile = blockIdx.x;
    const int l = threadIdx.x;
    const int ks = tile & 15, rt = (tile >> 4) & 1, bk = (tile >> 5) & 63, mat = tile >> 11;
    const int r = rt * 16 + (l & 15);
    const int row = (r >> 3) * 512 + bk * 8 + (r & 7);
    const int k0 = ks * 32 + (l >> 4) * 8;
    const float* src = (mat ? Whh : Wih) + (size_t)row * 512 + k0;
    ushort_t* dst = wprep + ((size_t)tile * 64 + l) * 8;
#pragma unroll
    for (int j = 0; j < 8; ++j) {
        _Float16 v = (_Float16)src[j];
        dst[j] = __builtin_bit_cast(ushort_t, v);
    }
}

// ---------------------------------------------------------------------------
// Contention-free grid barrier (r5 gbar3, kept)
// ---------------------------------------------------------------------------
__device__ __forceinline__ void gbar3(unsigned* __restrict__ flags,
                                      unsigned* __restrict__ rel,
                                      unsigned ph)
{
    __syncthreads();
    if (blockIdx.x == 0) {
        if (threadIdx.x < 64) {
            if (threadIdx.x > 0) {
                while (__hip_atomic_load(&flags[threadIdx.x * 32],
                                         __ATOMIC_RELAXED, __HIP_MEMORY_SCOPE_AGENT) < ph)
                    __builtin_amdgcn_s_sleep(1);
            }
            __hip_atomic_store(&rel[threadIdx.x * 32], ph,
                               __ATOMIC_RELAXED, __HIP_MEMORY_SCOPE_AGENT);
        }
    } else {
        if (threadIdx.x == 0) {
            __hip_atomic_store(&flags[blockIdx.x * 32], ph,
                               __ATOMIC_RELAXED, __HIP_MEMORY_SCOPE_AGENT);
            while (__hip_atomic_load(&rel[blockIdx.x * 32],
                                     __ATOMIC_RELAXED, __HIP_MEMORY_SCOPE_AGENT) < ph)
                __builtin_amdgcn_s_sleep(1);
        }
    }
    __syncthreads();
}

// ---------------------------------------------------------------------------
// MFMA LSTM recurrence (unchanged from r6)
// ---------------------------------------------------------------------------
__launch_bounds__(512, 1)
__global__ void lstm_rec(const float* __restrict__ g1x,
                         const ushort_t* __restrict__ wprep,
                         const float* __restrict__ bih,
                         const float* __restrict__ bhh,
                         ushort_t* __restrict__ h1h,   // 42 x 16 x 512 f16
                         ushort_t* __restrict__ h2h,   // 42 x 16 x 512 f16
                         float* __restrict__ h2f,      // 42 x 16 x 512 f32
                         unsigned* __restrict__ barflags)
{
    __shared__ _Float16 Hs1[16 * 520];
    __shared__ _Float16 Hs2[16 * 520];
    __shared__ float G1S[512];
    __shared__ float Dlds[3][32 * 17];
    __shared__ float C1S[128];
    __shared__ float C2S[128];

    const int bk = blockIdx.x;
    const int tid = threadIdx.x;
    const int w = tid >> 6, lane = tid & 63;
    unsigned* rel = barflags + 2048;

    if (tid < 128) { C1S[tid] = 0.f; C2S[tid] = 0.f; }

    float bs[4][2];
    if (tid >= 64 && tid < 128) {
        int up = (tid - 64) >> 4;
#pragma unroll
        for (int q = 0; q < 4; ++q)
#pragma unroll
            for (int j = 0; j < 2; ++j) {
                int u = bk * 8 + up * 2 + j;
                bs[q][j] = bih[q * 512 + u] + bhh[q * 512 + u];
            }
    }

    const int p = w >> 1, rt = w & 1;
    const int mat = (p == 1) ? 0 : 1;
    const ushort_t* wbase = wprep + (((size_t)(mat * 2048 + bk * 32 + rt * 16)) * 64 + lane) * 8;
    const int boff = (lane & 15) * 520 + (lane >> 4) * 8;
    const int drow0 = rt * 16 + (lane >> 4) * 4, dcol = lane & 15;

    for (int k = 0; k <= NS; ++k) {
        const bool doC1 = (k < NS);
        const bool doC2 = (k > 0);
        {
#pragma unroll
            for (int j = 0; j < 2; ++j) {
                int idx = tid + j * 512;
                int batch = idx >> 6, off = (idx & 63) * 8;
                uint4 v1 = *(const uint4*)(h1h + (size_t)k * 8192 + idx * 8);
                *(uint4*)(Hs1 + batch * 520 + off) = v1;
                if (doC2) {
                    uint4 v2 = *(const uint4*)(h2h + (size_t)(k - 1) * 8192 + idx * 8);
                    *(uint4*)(Hs2 + batch * 520 + off) = v2;
                }
            }
            if (doC1) {
                int r = tid >> 4, bb = tid & 15;
                int n = (r >> 3) * 512 + bk * 8 + (r & 7);
                G1S[tid] = g1x[(size_t)(k * 16 + bb) * 2048 + n];
            }
        }
        __syncthreads();
        if (w < 6 && (p == 0 ? doC1 : doC2)) {
            const _Float16* hs = (p == 2) ? Hs2 : Hs1;
            f32x4 acc = {0.f, 0.f, 0.f, 0.f};
#pragma unroll
            for (int ks = 0; ks < 16; ++ks) {
                f16x8 a = *(const f16x8*)(wbase + (size_t)ks * 512);
                f16x8 b = *(const f16x8*)(hs + boff + ks * 32);
                acc = __builtin_amdgcn_mfma_f32_16x16x32_f16(a, b, acc, 0, 0, 0);
            }
#pragma unroll
            for (int r = 0; r < 4; ++r)
                Dlds[p][(drow0 + r) * 17 + dcol] = acc[r];
        }
        __syncthreads();
        if (tid < 64) {
            if (doC1) {
                int bb = tid & 15, up = tid >> 4;
                unsigned pk = 0;
#pragma unroll
                for (int j = 0; j < 2; ++j) {
                    int ul = up * 2 + j;
                    float gi = G1S[(0 * 8 + ul) * 16 + bb] + Dlds[0][(0 * 8 + ul) * 17 + bb];
                    float gf = G1S[(1 * 8 + ul) * 16 + bb] + Dlds[0][(1 * 8 + ul) * 17 + bb];
                    float gg = G1S[(2 * 8 + ul) * 16 + bb] + Dlds[0][(2 * 8 + ul) * 17 + bb];
                    float go = G1S[(3 * 8 + ul) * 16 + bb] + Dlds[0][(3 * 8 + ul) * 17 + bb];
                    float cn = fsig(gf) * C1S[bb * 8 + ul] + fsig(gi) * ftanhf(gg);
                    C1S[bb * 8 + ul] = cn;
                    _Float16 hv = (_Float16)(fsig(go) * ftanhf(cn));
                    pk |= (unsigned)__builtin_bit_cast(ushort_t, hv) << (16 * j);
                }
                unsigned* dst = (unsigned*)h1h;
                __hip_atomic_store(&dst[(size_t)((k + 1) * 16 + bb) * 256 + bk * 4 + up],
                                   pk, __ATOMIC_RELAXED, __HIP_MEMORY_SCOPE_AGENT);
            }
        } else if (tid < 128) {
            if (doC2) {
                int t2 = tid - 64;
                int bb = t2 & 15, up = t2 >> 4;
                unsigned pk = 0;
#pragma unroll
                for (int j = 0; j < 2; ++j) {
                    int ul = up * 2 + j;
                    float gi = bs[0][j] + Dlds[1][(0 * 8 + ul) * 17 + bb] + Dlds[2][(0 * 8 + ul) * 17 + bb];
                    float gf = bs[1][j] + Dlds[1][(1 * 8 + ul) * 17 + bb] + Dlds[2][(1 * 8 + ul) * 17 + bb];
                    float gg = bs[2][j] + Dlds[1][(2 * 8 + ul) * 17 + bb] + Dlds[2][(2 * 8 + ul) * 17 + bb];
                    float go = bs[3][j] + Dlds[1][(3 * 8 + ul) * 17 + bb] + Dlds[2][(3 * 8 + ul) * 17 + bb];
                    float cn = fsig(gf) * C2S[bb * 8 + ul] + fsig(gi) * ftanhf(gg);
                    C2S[bb * 8 + ul] = cn;
                    float hf = fsig(go) * ftanhf(cn);
                    h2f[(size_t)k * 8192 + bb * 512 + bk * 8 + ul] = hf;
                    _Float16 hv = (_Float16)hf;
                    pk |= (unsigned)__builtin_bit_cast(ushort_t, hv) << (16 * j);
                }
                unsigned* dst = (unsigned*)h2h;
                __hip_atomic_store(&dst[(size_t)(k * 16 + bb) * 256 + bk * 4 + up],
                                   pk, __ATOMIC_RELAXED, __HIP_MEMORY_SCOPE_AGENT);
            }
        }
        gbar3(barflags, rel, (unsigned)(k + 1));
    }
}

// ---------------------------------------------------------------------------
// Attention (conv2V now f16)
// ---------------------------------------------------------------------------
__launch_bounds__(256)
__global__ void attention_k(const _Float16* __restrict__ conv2Vh, const float* __restrict__ hproj,
                            const float* __restrict__ V, const float* __restrict__ w3,
                            const float* __restrict__ b3, float* __restrict__ attw_out,
                            float* __restrict__ glimpse)
{
    const int r = blockIdx.x;
    const int to = r >> 4, b = r & 15;
    const int tid = threadIdx.x;
    const _Float16* cb = conv2Vh + (size_t)b * 512 * 256;
    const float* hp = hproj + (size_t)r * 512;
    __shared__ float red[256];
    float acc = 0.f;
#pragma unroll 4
    for (int d = 0; d < 512; ++d) {
        float x = (float)cb[(size_t)d * 256 + tid] + hp[d];
        acc = fmaf(w3[d], ftanhf(x), acc);
    }
    float logit = acc + b3[0];
    red[tid] = logit; __syncthreads();
    for (int s = 128; s > 0; s >>= 1) { if (tid < s) red[tid] = fmaxf(red[tid], red[tid + s]); __syncthreads(); }
    float mx = red[0]; __syncthreads();
    float e = __expf(logit - mx);
    red[tid] = e; __syncthreads();
    for (int s = 128; s > 0; s >>= 1) { if (tid < s) red[tid] += red[tid + s]; __syncthreads(); }
    float aw = e / red[0];
    __syncthreads();
    attw_out[(size_t)b * 10240 + (size_t)to * 256 + tid] = aw;
    red[tid] = aw; __syncthreads();
    const float* Vb = V + (size_t)b * 512 * 256;
#pragma unroll
    for (int dl = 0; dl < 2; ++dl) {
        int d = tid + dl * 256;
        float g = 0.f;
        for (int p4 = 0; p4 < 256; p4 += 4) {
            float4 vv = *(const float4*)(Vb + (size_t)d * 256 + p4);
            g = fmaf(vv.x, red[p4], g);     g = fmaf(vv.y, red[p4 + 1], g);
            g = fmaf(vv.z, red[p4 + 2], g); g = fmaf(vv.w, red[p4 + 3], g);
        }
        glimpse[(size_t)r * 512 + d] = g;
    }
}

// feat[r][k] = k<512 ? h2f[r+32][k] : glimpse[r][k-512];  grid = 2560
__launch_bounds__(256)
__global__ void concat_feat(const float* __restrict__ h2f, const float* __restrict__ glimpse,
                            float* __restrict__ feat)
{
    int idx = blockIdx.x * 256 + threadIdx.x;
    int r = idx >> 10, k = idx & 1023;
    feat[idx] = (k < 512) ? h2f[(size_t)(r + 32) * 512 + k]
                          : glimpse[(size_t)r * 512 + (k - 512)];
}

// In-place log_softmax over rows of 7000. grid = 640
__launch_bounds__(256)
__global__ void logsoftmax_k(float* __restrict__ out)
{
    int r = blockIdx.x;
    int b = r & 15, to = r >> 4;
    float* row = out + (size_t)b * 280000 + (size_t)to * 7000;
    __shared__ float buf[7000];
    __shared__ float red[256];
    int tid = threadIdx.x;
    float mx = -1e30f;
    for (int i = tid; i < 7000; i += 256) { float v = row[i]; buf[i] = v; mx = fmaxf(mx, v); }
    red[tid] = mx; __syncthreads();
    for (int s = 128; s > 0; s >>= 1) { if (tid < s) red[tid] = fmaxf(red[tid], red[tid + s]); __syncthreads(); }
    mx = red[0]; __syncthreads();
    float sm = 0.f;
    for (int i = tid; i < 7000; i += 256) sm += __expf(buf[i] - mx);
    red[tid] = sm; __syncthreads();
    for (int s = 128; s > 0; s >>= 1) { if (tid < s) red[tid] += red[tid + s]; __syncthreads(); }
    float lse = mx + __logf(red[0]);
    for (int i = tid; i < 7000; i += 256) row[i] = buf[i] - lse;
}

// ---------------------------------------------------------------------------
extern "C" void kernel_launch(void* const* d_in, const int* in_sizes, int n_in,
                              void* d_out, int out_size, void* d_ws, size_t ws_size,
                              hipStream_t stream)
{
    const float* hw      = (const float*)d_in[0];
    const float* y       = (const float*)d_in[1];
    const float* V       = (const float*)d_in[2];
    const float* w_lin1  = (const float*)d_in[3];
    const float* b_lin1  = (const float*)d_in[4];
    const float* W_ih    = (const float*)d_in[5];
    const float* b_ih    = (const float*)d_in[6];
    const float* W_hh    = (const float*)d_in[7];
    const float* b_hh    = (const float*)d_in[8];
    const float* w_conv1 = (const float*)d_in[9];
    const float* b_conv1 = (const float*)d_in[10];
    const float* w_conv2 = (const float*)d_in[11];
    const float* b_conv2 = (const float*)d_in[12];
    const float* w_conv3 = (const float*)d_in[13];
    const float* b_conv3 = (const float*)d_in[14];
    const float* w_lin2  = (const float*)d_in[15];
    const float* b_lin2  = (const float*)d_in[16];
    float* out = (float*)d_out;

    float* ws = (float*)d_ws;
    float* xs_tf   = ws + 0;                        // 319488
    unsigned* barflags = (unsigned*)(ws + 319488);  // 4096 uints
    float* h2f     = ws + 323584;                   // 344064
    float* xs      = ws + 667648;                   // 335872
    float* g1x     = ws + 1003520;                  // 1343488
    ushort_t* conv2Vh = (ushort_t*)(ws + 2347008);  // 2,097,152 f16 = 1,048,576 floats
    ushort_t* wconv   = (ushort_t*)(ws + 3395584);  // 2,359,296 f16 = 1,179,648 floats
    float* hproj   = ws + 4575232;                  // 327680
    float* glimpse = ws + 4902912;                  // 327680
    float* feat    = ws + 5230592;                  // 655360 -> 5885952
    // lstm wprep (2,097,152 f16 = 1,048,576 floats) aliases hproj/glimpse/feat
    ushort_t* wprep = (ushort_t*)(ws + 4575232);
    ushort_t* h1h  = (ushort_t*)(ws + 5885952);     // 86016 floats
    ushort_t* h2h  = (ushort_t*)(ws + 5971968);     // 86016 floats -> end 6057984

    // zero: xs_tf (split-K accum) + barflags ; h1h slot0 ; h2h slot0
    hipMemsetAsync(ws, 0, (size_t)323584 * sizeof(float), stream);
    hipMemsetAsync(h1h, 0, 16384, stream);
    hipMemsetAsync(h2h, 0, 16384, stream);

    // xs_tf = y @ w_lin1^T   (624 x 512, K=7000, split-K=8)
    gemm_tn<<<dim3(10, 8, 8), 256, 0, stream>>>(y, w_lin1, xs_tf, 624, 512, 7000,
                                                7000, 7000, 512, nullptr, nullptr, 0, 8);
    build_xs<<<656, 256, 0, stream>>>(hw, xs_tf, w_lin1, b_lin1, xs);
    // g1x = xs @ W_ih^T + b_ih + b_hh   (656 x 2048, K=512)
    gemm_tn<<<dim3(11, 32, 1), 256, 0, stream>>>(xs, W_ih, g1x, 656, 2048, 512,
                                                 512, 512, 2048, b_ih, b_hh, 0, 1);
    // conv weights prep + MFMA conv
    wconvprep_k<<<4608, 64, 0, stream>>>(w_conv2, wconv);
    conv_mfma<<<256, 256, 0, stream>>>(V, wconv, b_conv2, conv2Vh);
    // LSTM weight fragment prep (f16 swizzle)
    wprep_k<<<4096, 64, 0, stream>>>(W_ih, W_hh, wprep);

    // sequential recurrence (cooperative, 42 phases, MFMA gates)
    void* args[] = {(void*)&g1x, (void*)&wprep, (void*)&b_ih, (void*)&b_hh,
                    (void*)&h1h, (void*)&h2h, (void*)&h2f, (void*)&barflags};
    hipLaunchCooperativeKernel((void*)lstm_rec, dim3(LSTM_NB), dim3(512), args, 0, stream);

    // hproj = h2[steps 1..40] @ w1^T + b_conv1   (640 x 512, K=512)
    gemm_tn<<<dim3(10, 8, 1), 256, 0, stream>>>(h2f + 2 * 8192, w_conv1, hproj,
                                                640, 512, 512, 512, 512, 512,
                                                b_conv1, nullptr, 0, 1);
    attention_k<<<640, 256, 0, stream>>>((const _Float16*)conv2Vh, hproj, V, w_conv3, b_conv3,
                                         out + 4480000, glimpse);
    concat_feat<<<2560, 256, 0, stream>>>(h2f, glimpse, feat);
    gemm_tn<<<dim3(10, 110, 1), 256, 0, stream>>>(feat, w_lin2, out, 640, 7000, 1024,
                                                  1024, 1024, 7000, b_lin2, nullptr, 2, 1);
    logsoftmax_k<<<640, 256, 0, stream>>>(out);
}

// Round 8
// 549.665 us; speedup vs baseline: 3.3506x; 1.3908x over previous
//
#include <hip/hip_runtime.h>

// Problem constants: B=16, H=8, W=32, D=512, HID=512, C=7000, T=40 (41 steps)
#define NS 41
#define LSTM_NB 64

typedef _Float16 f16x8 __attribute__((ext_vector_type(8)));
typedef float f32x4 __attribute__((ext_vector_type(4)));
typedef unsigned short ushort_t;

__device__ __forceinline__ float fsig(float x) { return 1.0f / (1.0f + __expf(-x)); }
__device__ __forceinline__ float ftanhf(float x) {
    float t = __expf(fminf(fmaxf(2.0f * x, -30.0f), 30.0f));
    return 1.0f - 2.0f / (t + 1.0f);
}

// ---------------------------------------------------------------------------
// f32 -> f16 conversion with row padding (dst row length dcols >= cols, pad 0)
// ---------------------------------------------------------------------------
__launch_bounds__(256)
__global__ void cvt16(const float* __restrict__ src, ushort_t* __restrict__ dst,
                      int rows, int cols, int dcols)
{
    int total = rows * dcols;
    for (int idx = blockIdx.x * 256 + threadIdx.x; idx < total; idx += gridDim.x * 256) {
        int r = idx / dcols, c = idx - r * dcols;
        _Float16 v = (c < cols) ? (_Float16)src[(size_t)r * cols + c] : (_Float16)0.f;
        dst[idx] = __builtin_bit_cast(ushort_t, v);
    }
}

// ---------------------------------------------------------------------------
// MFMA f16 TN GEMM: C[m,n] = sum_k A[m,k]*B[n,k] (+bias[n]+bias2[n])
// A from Ah (f16) or Af (f32, converted during staging); same for B.
// 64x64 tile, K-chunk 64, register-prefetch double buffer.
// ksplit>1: split-K, atomicAdd into pre-zeroed C (no bias).
// cmode==2: store to C[(m&15)*280000 + (m>>4)*7000 + n].
// Fragment layouts (HW-verified in earlier rounds):
//   A/B operand: lane l holds row/col (l&15), k = (l>>4)*8 + j
//   D: m-within-tile = (l>>4)*4 + r, n-within-tile = l&15
// ---------------------------------------------------------------------------
__launch_bounds__(256)
__global__ void gemm16(const float* __restrict__ Af, const _Float16* __restrict__ Ah,
                       const float* __restrict__ Bf, const _Float16* __restrict__ Bh,
                       float* __restrict__ C, int M, int N, int K,
                       int lda, int ldb, int ldc,
                       const float* __restrict__ bias, const float* __restrict__ bias2,
                       int cmode, int ksplit)
{
    __shared__ _Float16 As[64][72];
    __shared__ _Float16 Bs[64][72];
    const int tid = threadIdx.x;
    const int m0 = blockIdx.x * 64, n0 = blockIdx.y * 64;
    int ck = K, kb0 = 0;
    if (ksplit > 1) {
        ck = (((K + ksplit - 1) / ksplit) + 63) & ~63;
        kb0 = blockIdx.z * ck;
    }
    const int kend = min(K, kb0 + ck);
    const int w = tid >> 6, lane = tid & 63;
    const int mh = (w >> 1) * 32, nh = (w & 1) * 32;
    const int lr = lane & 15;
    const int srow = tid >> 2, skq = tid & 3;
    const int gm = m0 + srow, gn = n0 + srow;

    f32x4 acc[2][2] = {};
    _Float16 ar[16], br[16];

    auto ldA = [&](int kb) {
        int ka = kb + skq * 16;
        if (gm < M && ka + 16 <= kend) {
            if (Ah) {
                const _Float16* p = Ah + (size_t)gm * lda + ka;
                *(uint4*)&ar[0] = *(const uint4*)p;
                *(uint4*)&ar[8] = *(const uint4*)(p + 8);
            } else {
                const float* p = Af + (size_t)gm * lda + ka;
                float4 v0 = *(const float4*)p, v1 = *(const float4*)(p + 4);
                float4 v2 = *(const float4*)(p + 8), v3 = *(const float4*)(p + 12);
                ar[0]=(_Float16)v0.x; ar[1]=(_Float16)v0.y; ar[2]=(_Float16)v0.z; ar[3]=(_Float16)v0.w;
                ar[4]=(_Float16)v1.x; ar[5]=(_Float16)v1.y; ar[6]=(_Float16)v1.z; ar[7]=(_Float16)v1.w;
                ar[8]=(_Float16)v2.x; ar[9]=(_Float16)v2.y; ar[10]=(_Float16)v2.z; ar[11]=(_Float16)v2.w;
                ar[12]=(_Float16)v3.x; ar[13]=(_Float16)v3.y; ar[14]=(_Float16)v3.z; ar[15]=(_Float16)v3.w;
            }
        } else {
#pragma unroll
            for (int j = 0; j < 16; ++j) {
                bool ok = (gm < M) && (ka + j >= 0) && (ka + j < kend);
                ar[j] = ok ? (Ah ? Ah[(size_t)gm * lda + ka + j]
                                 : (_Float16)Af[(size_t)gm * lda + ka + j])
                           : (_Float16)0.f;
            }
        }
    };
    auto ldB = [&](int kb) {
        int ka = kb + skq * 16;
        if (gn < N && ka + 16 <= kend) {
            if (Bh) {
                const _Float16* p = Bh + (size_t)gn * ldb + ka;
                *(uint4*)&br[0] = *(const uint4*)p;
                *(uint4*)&br[8] = *(const uint4*)(p + 8);
            } else {
                const float* p = Bf + (size_t)gn * ldb + ka;
                float4 v0 = *(const float4*)p, v1 = *(const float4*)(p + 4);
                float4 v2 = *(const float4*)(p + 8), v3 = *(const float4*)(p + 12);
                br[0]=(_Float16)v0.x; br[1]=(_Float16)v0.y; br[2]=(_Float16)v0.z; br[3]=(_Float16)v0.w;
                br[4]=(_Float16)v1.x; br[5]=(_Float16)v1.y; br[6]=(_Float16)v1.z; br[7]=(_Float16)v1.w;
                br[8]=(_Float16)v2.x; br[9]=(_Float16)v2.y; br[10]=(_Float16)v2.z; br[11]=(_Float16)v2.w;
                br[12]=(_Float16)v3.x; br[13]=(_Float16)v3.y; br[14]=(_Float16)v3.z; br[15]=(_Float16)v3.w;
            }
        } else {
#pragma unroll
            for (int j = 0; j < 16; ++j) {
                bool ok = (gn < N) && (ka + j >= 0) && (ka + j < kend);
                br[j] = ok ? (Bh ? Bh[(size_t)gn * ldb + ka + j]
                                 : (_Float16)Bf[(size_t)gn * ldb + ka + j])
                           : (_Float16)0.f;
            }
        }
    };

    ldA(kb0); ldB(kb0);
    for (int kb = kb0; kb < kend; kb += 64) {
        __syncthreads();
        *(uint4*)&As[srow][skq * 16]     = *(uint4*)&ar[0];
        *(uint4*)&As[srow][skq * 16 + 8] = *(uint4*)&ar[8];
        *(uint4*)&Bs[srow][skq * 16]     = *(uint4*)&br[0];
        *(uint4*)&Bs[srow][skq * 16 + 8] = *(uint4*)&br[8];
        __syncthreads();
        if (kb + 64 < kend) { ldA(kb + 64); ldB(kb + 64); }
#pragma unroll
        for (int kc = 0; kc < 2; ++kc) {
            int lk = (lane >> 4) * 8 + kc * 32;
            f16x8 af0 = *(const f16x8*)&As[mh + lr][lk];
            f16x8 af1 = *(const f16x8*)&As[mh + 16 + lr][lk];
            f16x8 bf0 = *(const f16x8*)&Bs[nh + lr][lk];
            f16x8 bf1 = *(const f16x8*)&Bs[nh + 16 + lr][lk];
            acc[0][0] = __builtin_amdgcn_mfma_f32_16x16x32_f16(af0, bf0, acc[0][0], 0, 0, 0);
            acc[0][1] = __builtin_amdgcn_mfma_f32_16x16x32_f16(af0, bf1, acc[0][1], 0, 0, 0);
            acc[1][0] = __builtin_amdgcn_mfma_f32_16x16x32_f16(af1, bf0, acc[1][0], 0, 0, 0);
            acc[1][1] = __builtin_amdgcn_mfma_f32_16x16x32_f16(af1, bf1, acc[1][1], 0, 0, 0);
        }
    }

#pragma unroll
    for (int mt = 0; mt < 2; ++mt)
#pragma unroll
    for (int nt = 0; nt < 2; ++nt) {
#pragma unroll
        for (int r = 0; r < 4; ++r) {
            int m = m0 + mh + mt * 16 + (lane >> 4) * 4 + r;
            int n = n0 + nh + nt * 16 + lr;
            if (m < M && n < N) {
                float v = acc[mt][nt][r];
                if (ksplit > 1) {
                    atomicAdd(&C[(size_t)m * ldc + n], v);
                } else {
                    if (bias)  v += bias[n];
                    if (bias2) v += bias2[n];
                    if (cmode == 2)
                        C[(size_t)(m & 15) * 280000 + (size_t)(m >> 4) * 7000 + n] = v;
                    else
                        C[(size_t)m * ldc + n] = v;
                }
            }
        }
    }
}

// ---------------------------------------------------------------------------
__launch_bounds__(256)
__global__ void build_xs(const float* __restrict__ hw, const float* __restrict__ xs_tf,
                         const float* __restrict__ w_lin1, const float* __restrict__ b_lin1,
                         float* __restrict__ xs)
{
    int blk = blockIdx.x;
    int t = blk >> 4, b = blk & 15;
    for (int h = threadIdx.x; h < 512; h += 256) {
        float v;
        if (t == 0)      v = hw[b * 512 + h];
        else if (t == 1) v = w_lin1[(size_t)h * 7000 + 6997] + b_lin1[h];
        else             v = xs_tf[((size_t)b * 39 + (t - 2)) * 512 + h] + b_lin1[h];
        xs[((size_t)t * 16 + b) * 512 + h] = v;
    }
}

// ---------------------------------------------------------------------------
// Conv weight prep (unchanged from r7)
// ---------------------------------------------------------------------------
__launch_bounds__(64)
__global__ void wconvprep_k(const float* __restrict__ w2, ushort_t* __restrict__ wconv)
{
    const int tile = blockIdx.x;              // 32*9*16 = 4608
    const int l = threadIdx.x;
    const int dt2 = tile / 144, rem = tile - dt2 * 144;
    const int tap = rem >> 4, kc = rem & 15;
    const int d = dt2 * 16 + (l & 15);
    const int c0 = kc * 32 + (l >> 4) * 8;
    ushort_t* dst = wconv + ((size_t)tile * 64 + l) * 8;
#pragma unroll
    for (int j = 0; j < 8; ++j) {
        _Float16 v = (_Float16)w2[((size_t)d * 512 + c0 + j) * 9 + tap];
        dst[j] = __builtin_bit_cast(ushort_t, v);
    }
}

// ---------------------------------------------------------------------------
// MFMA 3x3 conv (unchanged from r7)
// ---------------------------------------------------------------------------
#define CROWS 340
__launch_bounds__(256)
__global__ void conv_mfma(const float* __restrict__ V, const ushort_t* __restrict__ wconv,
                          const float* __restrict__ b2, ushort_t* __restrict__ outh)
{
    __shared__ _Float16 Vt2[CROWS * 32];
    const int blk = blockIdx.x;
    const int b = blk >> 4, dt = blk & 15;
    const int tid = threadIdx.x;
    const int w = tid >> 6, lane = tid & 63;
    const int col = lane & 15, kg = lane >> 4;

    for (int r = tid; r < CROWS; r += 256) {
        int hh = r / 34, ww = r - hh * 34;
        if (hh == 0 || hh == 9 || ww == 0 || ww == 33) {
            uint4 z = {0u, 0u, 0u, 0u};
            *(uint4*)&Vt2[r * 32]      = z;
            *(uint4*)&Vt2[r * 32 + 8]  = z;
            *(uint4*)&Vt2[r * 32 + 16] = z;
            *(uint4*)&Vt2[r * 32 + 24] = z;
        }
    }

    int rbase[4];
#pragma unroll
    for (int nt = 0; nt < 4; ++nt) {
        int n = (w * 4 + nt) * 16 + col;
        int hh = n >> 5, ww = n & 31;
        rbase[nt] = (hh * 34 + ww) * 32 + kg * 8;
    }

    const int cc = tid & 31, pg = tid >> 5;
    f32x4 acc0[4] = {}, acc1[4] = {};

    for (int c0 = 0; c0 < 512; c0 += 32) {
        const float* s = V + (((size_t)b * 512 + c0 + cc) * 256) + pg * 32;
        const int browbase = ((pg + 1) * 34 + 1) * 32 + cc;
#pragma unroll
        for (int j4 = 0; j4 < 8; ++j4) {
            float4 v4 = *(const float4*)(s + j4 * 4);
            Vt2[browbase + (j4 * 4 + 0) * 32] = (_Float16)v4.x;
            Vt2[browbase + (j4 * 4 + 1) * 32] = (_Float16)v4.y;
            Vt2[browbase + (j4 * 4 + 2) * 32] = (_Float16)v4.z;
            Vt2[browbase + (j4 * 4 + 3) * 32] = (_Float16)v4.w;
        }
        __syncthreads();
        const int kc = c0 >> 5;
#pragma unroll
        for (int tap = 0; tap < 9; ++tap) {
            const int kh = tap / 3, kw = tap - kh * 3;
            const int toff = (kh * 34 + kw) * 32;
            f16x8 a0 = *(const f16x8*)(wconv + ((((size_t)(dt * 2 + 0) * 9 + tap) * 16 + kc) * 64 + lane) * 8);
            f16x8 a1 = *(const f16x8*)(wconv + ((((size_t)(dt * 2 + 1) * 9 + tap) * 16 + kc) * 64 + lane) * 8);
#pragma unroll
            for (int nt = 0; nt < 4; ++nt) {
                f16x8 bf = *(const f16x8*)&Vt2[rbase[nt] + toff];
                acc0[nt] = __builtin_amdgcn_mfma_f32_16x16x32_f16(a0, bf, acc0[nt], 0, 0, 0);
                acc1[nt] = __builtin_amdgcn_mfma_f32_16x16x32_f16(a1, bf, acc1[nt], 0, 0, 0);
            }
        }
        __syncthreads();
    }

    float bv0[4], bv1[4];
#pragma unroll
    for (int r = 0; r < 4; ++r) {
        bv0[r] = b2[dt * 32 + kg * 4 + r];
        bv1[r] = b2[dt * 32 + 16 + kg * 4 + r];
    }
#pragma unroll
    for (int nt = 0; nt < 4; ++nt) {
        int p = (w * 4 + nt) * 16 + col;
#pragma unroll
        for (int r = 0; r < 4; ++r) {
            int d0 = dt * 32 + kg * 4 + r;
            int d1 = d0 + 16;
            _Float16 o0 = (_Float16)(acc0[nt][r] + bv0[r]);
            _Float16 o1 = (_Float16)(acc1[nt][r] + bv1[r]);
            outh[((size_t)b * 512 + d0) * 256 + p] = __builtin_bit_cast(ushort_t, o0);
            outh[((size_t)b * 512 + d1) * 256 + p] = __builtin_bit_cast(ushort_t, o1);
        }
    }
}

// ---------------------------------------------------------------------------
// LSTM weight prep (unchanged)
// ---------------------------------------------------------------------------
__launch_bounds__(64)
__global__ void wprep_k(const float* __restrict__ Wih, const float* __restrict__ Whh,
                        ushort_t* __restrict__ wprep)
{
    const int tile = blockIdx.x;
    const int l = threadIdx.x;
    const int ks = tile & 15, rt = (tile >> 4) & 1, bk = (tile >> 5) & 63, mat = tile >> 11;
    const int r = rt * 16 + (l & 15);
    const int row = (r >> 3) * 512 + bk * 8 + (r & 7);
    const int k0 = ks * 32 + (l >> 4) * 8;
    const float* src = (mat ? Whh : Wih) + (size_t)row * 512 + k0;
    ushort_t* dst = wprep + ((size_t)tile * 64 + l) * 8;
#pragma unroll
    for (int j = 0; j < 8; ++j) {
        _Float16 v = (_Float16)src[j];
        dst[j] = __builtin_bit_cast(ushort_t, v);
    }
}

// ---------------------------------------------------------------------------
// Contention-free grid barrier (unchanged)
// ---------------------------------------------------------------------------
__device__ __forceinline__ void gbar3(unsigned* __restrict__ flags,
                                      unsigned* __restrict__ rel,
                                      unsigned ph)
{
    __syncthreads();
    if (blockIdx.x == 0) {
        if (threadIdx.x < 64) {
            if (threadIdx.x > 0) {
                while (__hip_atomic_load(&flags[threadIdx.x * 32],
                                         __ATOMIC_RELAXED, __HIP_MEMORY_SCOPE_AGENT) < ph)
                    __builtin_amdgcn_s_sleep(1);
            }
            __hip_atomic_store(&rel[threadIdx.x * 32], ph,
                               __ATOMIC_RELAXED, __HIP_MEMORY_SCOPE_AGENT);
        }
    } else {
        if (threadIdx.x == 0) {
            __hip_atomic_store(&flags[blockIdx.x * 32], ph,
                               __ATOMIC_RELAXED, __HIP_MEMORY_SCOPE_AGENT);
            while (__hip_atomic_load(&rel[blockIdx.x * 32],
                                     __ATOMIC_RELAXED, __HIP_MEMORY_SCOPE_AGENT) < ph)
                __builtin_amdgcn_s_sleep(1);
        }
    }
    __syncthreads();
}

// ---------------------------------------------------------------------------
// MFMA LSTM recurrence (r6 structure; h2f removed, proper buffer sizes)
// ---------------------------------------------------------------------------
__launch_bounds__(512, 1)
__global__ void lstm_rec(const float* __restrict__ g1x,
                         const ushort_t* __restrict__ wprep,
                         const float* __restrict__ bih,
                         const float* __restrict__ bhh,
                         ushort_t* __restrict__ h1h,   // 42 x 16 x 512 f16
                         ushort_t* __restrict__ h2h,   // 42 x 16 x 512 f16
                         unsigned* __restrict__ barflags)
{
    __shared__ _Float16 Hs1[16 * 520];
    __shared__ _Float16 Hs2[16 * 520];
    __shared__ float G1S[512];
    __shared__ float Dlds[3][32 * 17];
    __shared__ float C1S[128];
    __shared__ float C2S[128];

    const int bk = blockIdx.x;
    const int tid = threadIdx.x;
    const int w = tid >> 6, lane = tid & 63;
    unsigned* rel = barflags + 2048;

    if (tid < 128) { C1S[tid] = 0.f; C2S[tid] = 0.f; }

    float bs[4][2];
    if (tid >= 64 && tid < 128) {
        int up = (tid - 64) >> 4;
#pragma unroll
        for (int q = 0; q < 4; ++q)
#pragma unroll
            for (int j = 0; j < 2; ++j) {
                int u = bk * 8 + up * 2 + j;
                bs[q][j] = bih[q * 512 + u] + bhh[q * 512 + u];
            }
    }

    const int p = w >> 1, rt = w & 1;
    const int mat = (p == 1) ? 0 : 1;
    const ushort_t* wbase = wprep + (((size_t)(mat * 2048 + bk * 32 + rt * 16)) * 64 + lane) * 8;
    const int boff = (lane & 15) * 520 + (lane >> 4) * 8;
    const int drow0 = rt * 16 + (lane >> 4) * 4, dcol = lane & 15;

    for (int k = 0; k <= NS; ++k) {
        const bool doC1 = (k < NS);
        const bool doC2 = (k > 0);
        {
#pragma unroll
            for (int j = 0; j < 2; ++j) {
                int idx = tid + j * 512;
                int batch = idx >> 6, off = (idx & 63) * 8;
                uint4 v1 = *(const uint4*)(h1h + (size_t)k * 8192 + idx * 8);
                *(uint4*)(Hs1 + batch * 520 + off) = v1;
                if (doC2) {
                    uint4 v2 = *(const uint4*)(h2h + (size_t)(k - 1) * 8192 + idx * 8);
                    *(uint4*)(Hs2 + batch * 520 + off) = v2;
                }
            }
            if (doC1) {
                int r = tid >> 4, bb = tid & 15;
                int n = (r >> 3) * 512 + bk * 8 + (r & 7);
                G1S[tid] = g1x[(size_t)(k * 16 + bb) * 2048 + n];
            }
        }
        __syncthreads();
        if (w < 6 && (p == 0 ? doC1 : doC2)) {
            const _Float16* hs = (p == 2) ? Hs2 : Hs1;
            f32x4 acc = {0.f, 0.f, 0.f, 0.f};
#pragma unroll
            for (int ks = 0; ks < 16; ++ks) {
                f16x8 a = *(const f16x8*)(wbase + (size_t)ks * 512);
                f16x8 b = *(const f16x8*)(hs + boff + ks * 32);
                acc = __builtin_amdgcn_mfma_f32_16x16x32_f16(a, b, acc, 0, 0, 0);
            }
#pragma unroll
            for (int r = 0; r < 4; ++r)
                Dlds[p][(drow0 + r) * 17 + dcol] = acc[r];
        }
        __syncthreads();
        if (tid < 64) {
            if (doC1) {
                int bb = tid & 15, up = tid >> 4;
                unsigned pk = 0;
#pragma unroll
                for (int j = 0; j < 2; ++j) {
                    int ul = up * 2 + j;
                    float gi = G1S[(0 * 8 + ul) * 16 + bb] + Dlds[0][(0 * 8 + ul) * 17 + bb];
                    float gf = G1S[(1 * 8 + ul) * 16 + bb] + Dlds[0][(1 * 8 + ul) * 17 + bb];
                    float gg = G1S[(2 * 8 + ul) * 16 + bb] + Dlds[0][(2 * 8 + ul) * 17 + bb];
                    float go = G1S[(3 * 8 + ul) * 16 + bb] + Dlds[0][(3 * 8 + ul) * 17 + bb];
                    float cn = fsig(gf) * C1S[bb * 8 + ul] + fsig(gi) * ftanhf(gg);
                    C1S[bb * 8 + ul] = cn;
                    _Float16 hv = (_Float16)(fsig(go) * ftanhf(cn));
                    pk |= (unsigned)__builtin_bit_cast(ushort_t, hv) << (16 * j);
                }
                unsigned* dst = (unsigned*)h1h;
                __hip_atomic_store(&dst[(size_t)((k + 1) * 16 + bb) * 256 + bk * 4 + up],
                                   pk, __ATOMIC_RELAXED, __HIP_MEMORY_SCOPE_AGENT);
            }
        } else if (tid < 128) {
            if (doC2) {
                int t2 = tid - 64;
                int bb = t2 & 15, up = t2 >> 4;
                unsigned pk = 0;
#pragma unroll
                for (int j = 0; j < 2; ++j) {
                    int ul = up * 2 + j;
                    float gi = bs[0][j] + Dlds[1][(0 * 8 + ul) * 17 + bb] + Dlds[2][(0 * 8 + ul) * 17 + bb];
                    float gf = bs[1][j] + Dlds[1][(1 * 8 + ul) * 17 + bb] + Dlds[2][(1 * 8 + ul) * 17 + bb];
                    float gg = bs[2][j] + Dlds[1][(2 * 8 + ul) * 17 + bb] + Dlds[2][(2 * 8 + ul) * 17 + bb];
                    float go = bs[3][j] + Dlds[1][(3 * 8 + ul) * 17 + bb] + Dlds[2][(3 * 8 + ul) * 17 + bb];
                    float cn = fsig(gf) * C2S[bb * 8 + ul] + fsig(gi) * ftanhf(gg);
                    C2S[bb * 8 + ul] = cn;
                    _Float16 hv = (_Float16)(fsig(go) * ftanhf(cn));
                    pk |= (unsigned)__builtin_bit_cast(ushort_t, hv) << (16 * j);
                }
                unsigned* dst = (unsigned*)h2h;
                __hip_atomic_store(&dst[(size_t)(k * 16 + bb) * 256 + bk * 4 + up],
                                   pk, __ATOMIC_RELAXED, __HIP_MEMORY_SCOPE_AGENT);
            }
        }
        gbar3(barflags, rel, (unsigned)(k + 1));
    }
}

// ---------------------------------------------------------------------------
// Attention (unchanged)
// ---------------------------------------------------------------------------
__launch_bounds__(256)
__global__ void attention_k(const _Float16* __restrict__ conv2Vh, const float* __restrict__ hproj,
                            const float* __restrict__ V, const float* __restrict__ w3,
                            const float* __restrict__ b3, float* __restrict__ attw_out,
                            float* __restrict__ glimpse)
{
    const int r = blockIdx.x;
    const int to = r >> 4, b = r & 15;
    const int tid = threadIdx.x;
    const _Float16* cb = conv2Vh + (size_t)b * 512 * 256;
    const float* hp = hproj + (size_t)r * 512;
    __shared__ float red[256];
    float acc = 0.f;
#pragma unroll 4
    for (int d = 0; d < 512; ++d) {
        float x = (float)cb[(size_t)d * 256 + tid] + hp[d];
        acc = fmaf(w3[d], ftanhf(x), acc);
    }
    float logit = acc + b3[0];
    red[tid] = logit; __syncthreads();
    for (int s = 128; s > 0; s >>= 1) { if (tid < s) red[tid] = fmaxf(red[tid], red[tid + s]); __syncthreads(); }
    float mx = red[0]; __syncthreads();
    float e = __expf(logit - mx);
    red[tid] = e; __syncthreads();
    for (int s = 128; s > 0; s >>= 1) { if (tid < s) red[tid] += red[tid + s]; __syncthreads(); }
    float aw = e / red[0];
    __syncthreads();
    attw_out[(size_t)b * 10240 + (size_t)to * 256 + tid] = aw;
    red[tid] = aw; __syncthreads();
    const float* Vb = V + (size_t)b * 512 * 256;
#pragma unroll
    for (int dl = 0; dl < 2; ++dl) {
        int d = tid + dl * 256;
        float g = 0.f;
        for (int p4 = 0; p4 < 256; p4 += 4) {
            float4 vv = *(const float4*)(Vb + (size_t)d * 256 + p4);
            g = fmaf(vv.x, red[p4], g);     g = fmaf(vv.y, red[p4 + 1], g);
            g = fmaf(vv.z, red[p4 + 2], g); g = fmaf(vv.w, red[p4 + 3], g);
        }
        glimpse[(size_t)r * 512 + d] = g;
    }
}

// feat[r][k] = k<512 ? h2(f16)[r+32][k] : glimpse[r][k-512];  grid = 2560
__launch_bounds__(256)
__global__ void concat_feat(const ushort_t* __restrict__ h2h, const float* __restrict__ glimpse,
                            float* __restrict__ feat)
{
    int idx = blockIdx.x * 256 + threadIdx.x;
    int r = idx >> 10, k = idx & 1023;
    if (k < 512) {
        _Float16 hv = __builtin_bit_cast(_Float16, h2h[(size_t)(r + 32) * 512 + k]);
        feat[idx] = (float)hv;
    } else {
        feat[idx] = glimpse[(size_t)r * 512 + (k - 512)];
    }
}

// In-place log_softmax over rows of 7000. grid = 640
__launch_bounds__(256)
__global__ void logsoftmax_k(float* __restrict__ out)
{
    int r = blockIdx.x;
    int b = r & 15, to = r >> 4;
    float* row = out + (size_t)b * 280000 + (size_t)to * 7000;
    __shared__ float buf[7000];
    __shared__ float red[256];
    int tid = threadIdx.x;
    float mx = -1e30f;
    for (int i = tid; i < 7000; i += 256) { float v = row[i]; buf[i] = v; mx = fmaxf(mx, v); }
    red[tid] = mx; __syncthreads();
    for (int s = 128; s > 0; s >>= 1) { if (tid < s) red[tid] = fmaxf(red[tid], red[tid + s]); __syncthreads(); }
    mx = red[0]; __syncthreads();
    float sm = 0.f;
    for (int i = tid; i < 7000; i += 256) sm += __expf(buf[i] - mx);
    red[tid] = sm; __syncthreads();
    for (int s = 128; s > 0; s >>= 1) { if (tid < s) red[tid] += red[tid + s]; __syncthreads(); }
    float lse = mx + __logf(red[0]);
    for (int i = tid; i < 7000; i += 256) row[i] = buf[i] - lse;
}

// ---------------------------------------------------------------------------
extern "C" void kernel_launch(void* const* d_in, const int* in_sizes, int n_in,
                              void* d_out, int out_size, void* d_ws, size_t ws_size,
                              hipStream_t stream)
{
    const float* hw      = (const float*)d_in[0];
    const float* y       = (const float*)d_in[1];
    const float* V       = (const float*)d_in[2];
    const float* w_lin1  = (const float*)d_in[3];
    const float* b_lin1  = (const float*)d_in[4];
    const float* W_ih    = (const float*)d_in[5];
    const float* b_ih    = (const float*)d_in[6];
    const float* W_hh    = (const float*)d_in[7];
    const float* b_hh    = (const float*)d_in[8];
    const float* w_conv1 = (const float*)d_in[9];
    const float* b_conv1 = (const float*)d_in[10];
    const float* w_conv2 = (const float*)d_in[11];
    const float* b_conv2 = (const float*)d_in[12];
    const float* w_conv3 = (const float*)d_in[13];
    const float* b_conv3 = (const float*)d_in[14];
    const float* w_lin2  = (const float*)d_in[15];
    const float* b_lin2  = (const float*)d_in[16];
    float* out = (float*)d_out;

    float* ws = (float*)d_ws;
    // persistent layout (floats)
    float* xs_tf   = ws + 0;                         // 319,488
    unsigned* barflags = (unsigned*)(ws + 319488);   // 4,096
    float* xs      = ws + 323584;                    // 335,872
    float* g1x     = ws + 659456;                    // 1,343,488
    ushort_t* conv2Vh = (ushort_t*)(ws + 2002944);   // 1,048,576 f
    ushort_t* wconv   = (ushort_t*)(ws + 3051520);   // 1,179,648 f
    float* hproj   = ws + 4231168;                   // 327,680
    float* glimpse = ws + 4558848;                   // 327,680
    float* feat    = ws + 4886528;                   // 655,360
    ushort_t* h1h  = (ushort_t*)(ws + 5541888);      // 172,032 f (42*16*512 f16)
    ushort_t* h2h  = (ushort_t*)(ws + 5713920);      // 172,032 f  -> end 5,885,952 (23.5 MB)
    // transient aliases:
    //  yh/wlh live only between cvt16 and the y-GEMM; alias g1x..glimpse region
    ushort_t* yh   = (ushort_t*)(ws + 659456);       // 624*7040 f16 = 2,196,480 f
    ushort_t* wlh  = (ushort_t*)(ws + 2855936);      // 512*7040 f16 = 1,802,240 f -> 4,658,176
    //  wprep lives from wprep_k to lstm_rec; alias hproj..feat region
    ushort_t* wprep = (ushort_t*)(ws + 4231168);     // 1,048,576 f -> 5,279,744
    //  optional w_lin2 f16 (only if workspace is big enough)
    ushort_t* w2lh = (ushort_t*)(ws + 5885952);      // 3,584,000 f -> 9,469,952
    const bool big = ws_size >= (size_t)9469952 * sizeof(float);

    // zero xs_tf (split-K accumulator) + barflags; h1h/h2h slot 0
    hipMemsetAsync(ws, 0, (size_t)323584 * sizeof(float), stream);
    hipMemsetAsync(h1h, 0, 16384, stream);
    hipMemsetAsync(h2h, 0, 16384, stream);

    // f16 conversions
    cvt16<<<1024, 256, 0, stream>>>(y, yh, 624, 7000, 7040);
    cvt16<<<1024, 256, 0, stream>>>(w_lin1, wlh, 512, 7000, 7040);
    if (big) cvt16<<<1024, 256, 0, stream>>>(w_lin2, w2lh, 7000, 1024, 1024);

    // xs_tf = y @ w_lin1^T  (624x512, K=7040 padded, split-K=16, MFMA)
    gemm16<<<dim3(10, 8, 16), 256, 0, stream>>>(nullptr, (const _Float16*)yh,
                                                nullptr, (const _Float16*)wlh,
                                                xs_tf, 624, 512, 7040, 7040, 7040, 512,
                                                nullptr, nullptr, 0, 16);
    build_xs<<<656, 256, 0, stream>>>(hw, xs_tf, w_lin1, b_lin1, xs);
    // g1x = xs @ W_ih^T + b_ih + b_hh  (656x2048, K=512, MFMA, f32 srcs)
    gemm16<<<dim3(11, 32), 256, 0, stream>>>(xs, nullptr, W_ih, nullptr,
                                             g1x, 656, 2048, 512, 512, 512, 2048,
                                             b_ih, b_hh, 0, 1);
    // conv
    wconvprep_k<<<4608, 64, 0, stream>>>(w_conv2, wconv);
    conv_mfma<<<256, 256, 0, stream>>>(V, wconv, b_conv2, conv2Vh);
    // LSTM weight prep (after y-GEMM: wlh region is dead; wprep aliases hproj+)
    wprep_k<<<4096, 64, 0, stream>>>(W_ih, W_hh, wprep);

    // sequential recurrence
    void* args[] = {(void*)&g1x, (void*)&wprep, (void*)&b_ih, (void*)&b_hh,
                    (void*)&h1h, (void*)&h2h, (void*)&barflags};
    hipLaunchCooperativeKernel((void*)lstm_rec, dim3(LSTM_NB), dim3(512), args, 0, stream);

    // hproj = h2[steps 1..40] @ w1^T + b_conv1  (A = f16 h2h slots 2..41)
    gemm16<<<dim3(10, 8), 256, 0, stream>>>(nullptr, (const _Float16*)h2h + 32 * 512,
                                            w_conv1, nullptr,
                                            hproj, 640, 512, 512, 512, 512, 512,
                                            b_conv1, nullptr, 0, 1);
    attention_k<<<640, 256, 0, stream>>>((const _Float16*)conv2Vh, hproj, V, w_conv3, b_conv3,
                                         out + 4480000, glimpse);
    concat_feat<<<2560, 256, 0, stream>>>(h2h, glimpse, feat);
    // logits = feat @ w_lin2^T + b_lin2 -> out (remap) ; then log_softmax
    if (big)
        gemm16<<<dim3(10, 110), 256, 0, stream>>>(feat, nullptr,
                                                  nullptr, (const _Float16*)w2lh,
                                                  out, 640, 7000, 1024, 1024, 1024, 7000,
                                                  b_lin2, nullptr, 2, 1);
    else
        gemm16<<<dim3(10, 110), 256, 0, stream>>>(feat, nullptr,
                                                  w_lin2, nullptr,
                                                  out, 640, 7000, 1024, 1024, 1024, 7000,
                                                  b_lin2, nullptr, 2, 1);
    logsoftmax_k<<<640, 256, 0, stream>>>(out);
}

// Round 9
// 529.699 us; speedup vs baseline: 3.4769x; 1.0377x over previous
//
#include <hip/hip_runtime.h>

// Problem constants: B=16, H=8, W=32, D=512, HID=512, C=7000, T=40 (41 steps)
#define NS 41
#define LSTM_NB 64

typedef _Float16 f16x8 __attribute__((ext_vector_type(8)));
typedef float f32x4 __attribute__((ext_vector_type(4)));
typedef unsigned short ushort_t;

__device__ __forceinline__ float fsig(float x) { return 1.0f / (1.0f + __expf(-x)); }
__device__ __forceinline__ float ftanhf(float x) {
    float t = __expf(fminf(fmaxf(2.0f * x, -30.0f), 30.0f));
    return 1.0f - 2.0f / (t + 1.0f);
}

// ---------------------------------------------------------------------------
// f32 -> f16 with row padding
// ---------------------------------------------------------------------------
__launch_bounds__(256)
__global__ void cvt16(const float* __restrict__ src, ushort_t* __restrict__ dst,
                      int rows, int cols, int dcols)
{
    int total = rows * dcols;
    for (int idx = blockIdx.x * 256 + threadIdx.x; idx < total; idx += gridDim.x * 256) {
        int r = idx / dcols, c = idx - r * dcols;
        _Float16 v = (c < cols) ? (_Float16)src[(size_t)r * cols + c] : (_Float16)0.f;
        dst[idx] = __builtin_bit_cast(ushort_t, v);
    }
}

// y (624x7000) and w_lin1 (512x7000) -> one f16 [1136][7040] buffer. grid=1136
__launch_bounds__(256)
__global__ void cvt_yw(const float* __restrict__ y, const float* __restrict__ w1,
                       ushort_t* __restrict__ dst)
{
    int r = blockIdx.x;
    const float* s = (r < 624) ? (y + (size_t)r * 7000) : (w1 + (size_t)(r - 624) * 7000);
    ushort_t* d = dst + (size_t)r * 7040;
    for (int c = threadIdx.x; c < 7040; c += 256) {
        _Float16 v = (c < 7000) ? (_Float16)s[c] : (_Float16)0.f;
        d[c] = __builtin_bit_cast(ushort_t, v);
    }
}

// ---------------------------------------------------------------------------
// MFMA f16 TN GEMM. kmode: 0 = ksplit>1 -> atomicAdd; 1 = ksplit>1 -> slab z
// amode: 1 = A virtual feat: k<512 from Ah (f16, stride 512), else Af (f32).
// cmode==2: final-output remap store.
// ---------------------------------------------------------------------------
__launch_bounds__(256)
__global__ void gemm16(const float* __restrict__ Af, const _Float16* __restrict__ Ah,
                       const float* __restrict__ Bf, const _Float16* __restrict__ Bh,
                       float* __restrict__ C, int M, int N, int K,
                       int lda, int ldb, int ldc,
                       const float* __restrict__ bias, const float* __restrict__ bias2,
                       int cmode, int ksplit, int kmode, int slabstride, int amode)
{
    __shared__ _Float16 As[64][72];
    __shared__ _Float16 Bs[64][72];
    const int tid = threadIdx.x;
    const int m0 = blockIdx.x * 64, n0 = blockIdx.y * 64;
    int ck = K, kb0 = 0;
    if (ksplit > 1) {
        ck = (((K + ksplit - 1) / ksplit) + 63) & ~63;
        kb0 = blockIdx.z * ck;
    }
    const int kend = min(K, kb0 + ck);
    const int w = tid >> 6, lane = tid & 63;
    const int mh = (w >> 1) * 32, nh = (w & 1) * 32;
    const int lr = lane & 15;
    const int srow = tid >> 2, skq = tid & 3;
    const int gm = m0 + srow, gn = n0 + srow;

    f32x4 acc[2][2] = {};
    _Float16 ar[16], br[16];

    auto ldA = [&](int kb) {
        int ka = kb + skq * 16;
        if (amode == 1) {
            if (gm < M) {
                if (ka < 512) {
                    const _Float16* p = Ah + (size_t)gm * 512 + ka;
                    *(uint4*)&ar[0] = *(const uint4*)p;
                    *(uint4*)&ar[8] = *(const uint4*)(p + 8);
                } else {
                    const float* p = Af + (size_t)gm * 512 + (ka - 512);
                    float4 v0 = *(const float4*)p, v1 = *(const float4*)(p + 4);
                    float4 v2 = *(const float4*)(p + 8), v3 = *(const float4*)(p + 12);
                    ar[0]=(_Float16)v0.x; ar[1]=(_Float16)v0.y; ar[2]=(_Float16)v0.z; ar[3]=(_Float16)v0.w;
                    ar[4]=(_Float16)v1.x; ar[5]=(_Float16)v1.y; ar[6]=(_Float16)v1.z; ar[7]=(_Float16)v1.w;
                    ar[8]=(_Float16)v2.x; ar[9]=(_Float16)v2.y; ar[10]=(_Float16)v2.z; ar[11]=(_Float16)v2.w;
                    ar[12]=(_Float16)v3.x; ar[13]=(_Float16)v3.y; ar[14]=(_Float16)v3.z; ar[15]=(_Float16)v3.w;
                }
            } else {
#pragma unroll
                for (int j = 0; j < 16; ++j) ar[j] = (_Float16)0.f;
            }
            return;
        }
        if (gm < M && ka + 16 <= kend) {
            if (Ah) {
                const _Float16* p = Ah + (size_t)gm * lda + ka;
                *(uint4*)&ar[0] = *(const uint4*)p;
                *(uint4*)&ar[8] = *(const uint4*)(p + 8);
            } else {
                const float* p = Af + (size_t)gm * lda + ka;
                float4 v0 = *(const float4*)p, v1 = *(const float4*)(p + 4);
                float4 v2 = *(const float4*)(p + 8), v3 = *(const float4*)(p + 12);
                ar[0]=(_Float16)v0.x; ar[1]=(_Float16)v0.y; ar[2]=(_Float16)v0.z; ar[3]=(_Float16)v0.w;
                ar[4]=(_Float16)v1.x; ar[5]=(_Float16)v1.y; ar[6]=(_Float16)v1.z; ar[7]=(_Float16)v1.w;
                ar[8]=(_Float16)v2.x; ar[9]=(_Float16)v2.y; ar[10]=(_Float16)v2.z; ar[11]=(_Float16)v2.w;
                ar[12]=(_Float16)v3.x; ar[13]=(_Float16)v3.y; ar[14]=(_Float16)v3.z; ar[15]=(_Float16)v3.w;
            }
        } else {
#pragma unroll
            for (int j = 0; j < 16; ++j) {
                bool ok = (gm < M) && (ka + j < kend);
                ar[j] = ok ? (Ah ? Ah[(size_t)gm * lda + ka + j]
                                 : (_Float16)Af[(size_t)gm * lda + ka + j])
                           : (_Float16)0.f;
            }
        }
    };
    auto ldB = [&](int kb) {
        int ka = kb + skq * 16;
        if (gn < N && ka + 16 <= kend) {
            if (Bh) {
                const _Float16* p = Bh + (size_t)gn * ldb + ka;
                *(uint4*)&br[0] = *(const uint4*)p;
                *(uint4*)&br[8] = *(const uint4*)(p + 8);
            } else {
                const float* p = Bf + (size_t)gn * ldb + ka;
                float4 v0 = *(const float4*)p, v1 = *(const float4*)(p + 4);
                float4 v2 = *(const float4*)(p + 8), v3 = *(const float4*)(p + 12);
                br[0]=(_Float16)v0.x; br[1]=(_Float16)v0.y; br[2]=(_Float16)v0.z; br[3]=(_Float16)v0.w;
                br[4]=(_Float16)v1.x; br[5]=(_Float16)v1.y; br[6]=(_Float16)v1.z; br[7]=(_Float16)v1.w;
                br[8]=(_Float16)v2.x; br[9]=(_Float16)v2.y; br[10]=(_Float16)v2.z; br[11]=(_Float16)v2.w;
                br[12]=(_Float16)v3.x; br[13]=(_Float16)v3.y; br[14]=(_Float16)v3.z; br[15]=(_Float16)v3.w;
            }
        } else {
#pragma unroll
            for (int j = 0; j < 16; ++j) {
                bool ok = (gn < N) && (ka + j < kend);
                br[j] = ok ? (Bh ? Bh[(size_t)gn * ldb + ka + j]
                                 : (_Float16)Bf[(size_t)gn * ldb + ka + j])
                           : (_Float16)0.f;
            }
        }
    };

    ldA(kb0); ldB(kb0);
    for (int kb = kb0; kb < kend; kb += 64) {
        __syncthreads();
        *(uint4*)&As[srow][skq * 16]     = *(uint4*)&ar[0];
        *(uint4*)&As[srow][skq * 16 + 8] = *(uint4*)&ar[8];
        *(uint4*)&Bs[srow][skq * 16]     = *(uint4*)&br[0];
        *(uint4*)&Bs[srow][skq * 16 + 8] = *(uint4*)&br[8];
        __syncthreads();
        if (kb + 64 < kend) { ldA(kb + 64); ldB(kb + 64); }
#pragma unroll
        for (int kc = 0; kc < 2; ++kc) {
            int lk = (lane >> 4) * 8 + kc * 32;
            f16x8 af0 = *(const f16x8*)&As[mh + lr][lk];
            f16x8 af1 = *(const f16x8*)&As[mh + 16 + lr][lk];
            f16x8 bf0 = *(const f16x8*)&Bs[nh + lr][lk];
            f16x8 bf1 = *(const f16x8*)&Bs[nh + 16 + lr][lk];
            acc[0][0] = __builtin_amdgcn_mfma_f32_16x16x32_f16(af0, bf0, acc[0][0], 0, 0, 0);
            acc[0][1] = __builtin_amdgcn_mfma_f32_16x16x32_f16(af0, bf1, acc[0][1], 0, 0, 0);
            acc[1][0] = __builtin_amdgcn_mfma_f32_16x16x32_f16(af1, bf0, acc[1][0], 0, 0, 0);
            acc[1][1] = __builtin_amdgcn_mfma_f32_16x16x32_f16(af1, bf1, acc[1][1], 0, 0, 0);
        }
    }

#pragma unroll
    for (int mt = 0; mt < 2; ++mt)
#pragma unroll
    for (int nt = 0; nt < 2; ++nt) {
#pragma unroll
        for (int r = 0; r < 4; ++r) {
            int m = m0 + mh + mt * 16 + (lane >> 4) * 4 + r;
            int n = n0 + nh + nt * 16 + lr;
            if (m < M && n < N) {
                float v = acc[mt][nt][r];
                if (ksplit > 1) {
                    if (kmode == 1)
                        C[(size_t)blockIdx.z * slabstride + (size_t)m * ldc + n] = v;
                    else
                        atomicAdd(&C[(size_t)m * ldc + n], v);
                } else {
                    if (bias)  v += bias[n];
                    if (bias2) v += bias2[n];
                    if (cmode == 2)
                        C[(size_t)(m & 15) * 280000 + (size_t)(m >> 4) * 7000 + n] = v;
                    else
                        C[(size_t)m * ldc + n] = v;
                }
            }
        }
    }
}

// ---------------------------------------------------------------------------
// build_xs with fused slab reduction (nslab slabs of 319488 floats)
// ---------------------------------------------------------------------------
__launch_bounds__(256)
__global__ void build_xs(const float* __restrict__ hw, const float* __restrict__ slabs,
                         const float* __restrict__ w_lin1, const float* __restrict__ b_lin1,
                         float* __restrict__ xs, int nslab)
{
    int blk = blockIdx.x;
    int t = blk >> 4, b = blk & 15;
    for (int h = threadIdx.x; h < 512; h += 256) {
        float v;
        if (t == 0)      v = hw[b * 512 + h];
        else if (t == 1) v = w_lin1[(size_t)h * 7000 + 6997] + b_lin1[h];
        else {
            size_t idx = ((size_t)b * 39 + (t - 2)) * 512 + h;
            float s = 0.f;
            for (int z = 0; z < nslab; ++z) s += slabs[(size_t)z * 319488 + idx];
            v = s + b_lin1[h];
        }
        xs[((size_t)t * 16 + b) * 512 + h] = v;
    }
}

// ---------------------------------------------------------------------------
// Fused weight prep: blocks [0,4608) conv fragments, [4608,8704) LSTM fragments
// ---------------------------------------------------------------------------
__launch_bounds__(64)
__global__ void wprep_all(const float* __restrict__ w2, ushort_t* __restrict__ wconv,
                          const float* __restrict__ Wih, const float* __restrict__ Whh,
                          ushort_t* __restrict__ wprep)
{
    const int l = threadIdx.x;
    if (blockIdx.x < 4608) {
        const int tile = blockIdx.x;
        const int dt2 = tile / 144, rem = tile - dt2 * 144;
        const int tap = rem >> 4, kc = rem & 15;
        const int d = dt2 * 16 + (l & 15);
        const int c0 = kc * 32 + (l >> 4) * 8;
        ushort_t* dst = wconv + ((size_t)tile * 64 + l) * 8;
#pragma unroll
        for (int j = 0; j < 8; ++j) {
            _Float16 v = (_Float16)w2[((size_t)d * 512 + c0 + j) * 9 + tap];
            dst[j] = __builtin_bit_cast(ushort_t, v);
        }
    } else {
        const int tile = blockIdx.x - 4608;
        const int ks = tile & 15, rt = (tile >> 4) & 1, bk = (tile >> 5) & 63, mat = tile >> 11;
        const int r = rt * 16 + (l & 15);
        const int row = (r >> 3) * 512 + bk * 8 + (r & 7);
        const int k0 = ks * 32 + (l >> 4) * 8;
        const float* src = (mat ? Whh : Wih) + (size_t)row * 512 + k0;
        ushort_t* dst = wprep + ((size_t)tile * 64 + l) * 8;
#pragma unroll
        for (int j = 0; j < 8; ++j) {
            _Float16 v = (_Float16)src[j];
            dst[j] = __builtin_bit_cast(ushort_t, v);
        }
    }
}

// ---------------------------------------------------------------------------
// MFMA 3x3 conv; dt==0 blocks additionally persist V as f16 (Vh) if non-null
// ---------------------------------------------------------------------------
#define CROWS 340
__launch_bounds__(256)
__global__ void conv_mfma(const float* __restrict__ V, const ushort_t* __restrict__ wconv,
                          const float* __restrict__ b2, ushort_t* __restrict__ outh,
                          ushort_t* __restrict__ Vh)
{
    __shared__ _Float16 Vt2[CROWS * 32];
    const int blk = blockIdx.x;
    const int b = blk >> 4, dt = blk & 15;
    const int tid = threadIdx.x;
    const int w = tid >> 6, lane = tid & 63;
    const int col = lane & 15, kg = lane >> 4;

    for (int r = tid; r < CROWS; r += 256) {
        int hh = r / 34, ww = r - hh * 34;
        if (hh == 0 || hh == 9 || ww == 0 || ww == 33) {
            uint4 z = {0u, 0u, 0u, 0u};
            *(uint4*)&Vt2[r * 32]      = z;
            *(uint4*)&Vt2[r * 32 + 8]  = z;
            *(uint4*)&Vt2[r * 32 + 16] = z;
            *(uint4*)&Vt2[r * 32 + 24] = z;
        }
    }

    int rbase[4];
#pragma unroll
    for (int nt = 0; nt < 4; ++nt) {
        int n = (w * 4 + nt) * 16 + col;
        int hh = n >> 5, ww = n & 31;
        rbase[nt] = (hh * 34 + ww) * 32 + kg * 8;
    }

    const int cc = tid & 31, pg = tid >> 5;
    f32x4 acc0[4] = {}, acc1[4] = {};

    for (int c0 = 0; c0 < 512; c0 += 32) {
        const float* s = V + (((size_t)b * 512 + c0 + cc) * 256) + pg * 32;
        const int browbase = ((pg + 1) * 34 + 1) * 32 + cc;
        _Float16 hv[32];
#pragma unroll
        for (int j4 = 0; j4 < 8; ++j4) {
            float4 v4 = *(const float4*)(s + j4 * 4);
            hv[j4 * 4 + 0] = (_Float16)v4.x;
            hv[j4 * 4 + 1] = (_Float16)v4.y;
            hv[j4 * 4 + 2] = (_Float16)v4.z;
            hv[j4 * 4 + 3] = (_Float16)v4.w;
            Vt2[browbase + (j4 * 4 + 0) * 32] = hv[j4 * 4 + 0];
            Vt2[browbase + (j4 * 4 + 1) * 32] = hv[j4 * 4 + 1];
            Vt2[browbase + (j4 * 4 + 2) * 32] = hv[j4 * 4 + 2];
            Vt2[browbase + (j4 * 4 + 3) * 32] = hv[j4 * 4 + 3];
        }
        if (Vh && dt == 0) {
            ushort_t* d = Vh + (((size_t)b * 512 + c0 + cc) * 256) + pg * 32;
#pragma unroll
            for (int q = 0; q < 4; ++q)
                *(uint4*)(d + q * 8) = *(const uint4*)&hv[q * 8];
        }
        __syncthreads();
        const int kc = c0 >> 5;
#pragma unroll
        for (int tap = 0; tap < 9; ++tap) {
            const int kh = tap / 3, kw = tap - kh * 3;
            const int toff = (kh * 34 + kw) * 32;
            f16x8 a0 = *(const f16x8*)(wconv + ((((size_t)(dt * 2 + 0) * 9 + tap) * 16 + kc) * 64 + lane) * 8);
            f16x8 a1 = *(const f16x8*)(wconv + ((((size_t)(dt * 2 + 1) * 9 + tap) * 16 + kc) * 64 + lane) * 8);
#pragma unroll
            for (int nt = 0; nt < 4; ++nt) {
                f16x8 bf = *(const f16x8*)&Vt2[rbase[nt] + toff];
                acc0[nt] = __builtin_amdgcn_mfma_f32_16x16x32_f16(a0, bf, acc0[nt], 0, 0, 0);
                acc1[nt] = __builtin_amdgcn_mfma_f32_16x16x32_f16(a1, bf, acc1[nt], 0, 0, 0);
            }
        }
        __syncthreads();
    }

    float bv0[4], bv1[4];
#pragma unroll
    for (int r = 0; r < 4; ++r) {
        bv0[r] = b2[dt * 32 + kg * 4 + r];
        bv1[r] = b2[dt * 32 + 16 + kg * 4 + r];
    }
#pragma unroll
    for (int nt = 0; nt < 4; ++nt) {
        int p = (w * 4 + nt) * 16 + col;
#pragma unroll
        for (int r = 0; r < 4; ++r) {
            int d0 = dt * 32 + kg * 4 + r;
            int d1 = d0 + 16;
            _Float16 o0 = (_Float16)(acc0[nt][r] + bv0[r]);
            _Float16 o1 = (_Float16)(acc1[nt][r] + bv1[r]);
            outh[((size_t)b * 512 + d0) * 256 + p] = __builtin_bit_cast(ushort_t, o0);
            outh[((size_t)b * 512 + d1) * 256 + p] = __builtin_bit_cast(ushort_t, o1);
        }
    }
}

// ---------------------------------------------------------------------------
// All-poll-all grid barrier: one RT less than master/release.
// Thread 0 stores own flag FIRST (separate if: no divergence deadlock), then
// wave-0 lanes poll all other flag lines. Monotonic phases -> ">= ph" safe.
// ---------------------------------------------------------------------------
__device__ __forceinline__ void gbar4(unsigned* __restrict__ flags, unsigned ph)
{
    __syncthreads();   // drains vmcnt: h stores complete before flag store
    if (threadIdx.x == 0)
        __hip_atomic_store(&flags[blockIdx.x * 32], ph,
                           __ATOMIC_RELAXED, __HIP_MEMORY_SCOPE_AGENT);
    if (threadIdx.x < 64 && threadIdx.x != blockIdx.x) {
        while (__hip_atomic_load(&flags[threadIdx.x * 32],
                                 __ATOMIC_RELAXED, __HIP_MEMORY_SCOPE_AGENT) < ph)
            __builtin_amdgcn_s_sleep(1);
    }
    __syncthreads();
}

// ---------------------------------------------------------------------------
// MFMA LSTM recurrence (r8 structure + gbar4)
// ---------------------------------------------------------------------------
__launch_bounds__(512, 1)
__global__ void lstm_rec(const float* __restrict__ g1x,
                         const ushort_t* __restrict__ wprep,
                         const float* __restrict__ bih,
                         const float* __restrict__ bhh,
                         ushort_t* __restrict__ h1h,   // 42 x 16 x 512 f16
                         ushort_t* __restrict__ h2h,   // 42 x 16 x 512 f16
                         unsigned* __restrict__ barflags)
{
    __shared__ _Float16 Hs1[16 * 520];
    __shared__ _Float16 Hs2[16 * 520];
    __shared__ float G1S[512];
    __shared__ float Dlds[3][32 * 17];
    __shared__ float C1S[128];
    __shared__ float C2S[128];

    const int bk = blockIdx.x;
    const int tid = threadIdx.x;
    const int w = tid >> 6, lane = tid & 63;

    if (tid < 128) { C1S[tid] = 0.f; C2S[tid] = 0.f; }

    float bs[4][2];
    if (tid >= 64 && tid < 128) {
        int up = (tid - 64) >> 4;
#pragma unroll
        for (int q = 0; q < 4; ++q)
#pragma unroll
            for (int j = 0; j < 2; ++j) {
                int u = bk * 8 + up * 2 + j;
                bs[q][j] = bih[q * 512 + u] + bhh[q * 512 + u];
            }
    }

    const int p = w >> 1, rt = w & 1;
    const int mat = (p == 1) ? 0 : 1;
    const ushort_t* wbase = wprep + (((size_t)(mat * 2048 + bk * 32 + rt * 16)) * 64 + lane) * 8;
    const int boff = (lane & 15) * 520 + (lane >> 4) * 8;
    const int drow0 = rt * 16 + (lane >> 4) * 4, dcol = lane & 15;

    for (int k = 0; k <= NS; ++k) {
        const bool doC1 = (k < NS);
        const bool doC2 = (k > 0);
        {
#pragma unroll
            for (int j = 0; j < 2; ++j) {
                int idx = tid + j * 512;
                int batch = idx >> 6, off = (idx & 63) * 8;
                uint4 v1 = *(const uint4*)(h1h + (size_t)k * 8192 + idx * 8);
                *(uint4*)(Hs1 + batch * 520 + off) = v1;
                if (doC2) {
                    uint4 v2 = *(const uint4*)(h2h + (size_t)(k - 1) * 8192 + idx * 8);
                    *(uint4*)(Hs2 + batch * 520 + off) = v2;
                }
            }
            if (doC1) {
                int r = tid >> 4, bb = tid & 15;
                int n = (r >> 3) * 512 + bk * 8 + (r & 7);
                G1S[tid] = g1x[(size_t)(k * 16 + bb) * 2048 + n];
            }
        }
        __syncthreads();
        if (w < 6 && (p == 0 ? doC1 : doC2)) {
            const _Float16* hs = (p == 2) ? Hs2 : Hs1;
            f32x4 acc = {0.f, 0.f, 0.f, 0.f};
#pragma unroll
            for (int ks = 0; ks < 16; ++ks) {
                f16x8 a = *(const f16x8*)(wbase + (size_t)ks * 512);
                f16x8 b = *(const f16x8*)(hs + boff + ks * 32);
                acc = __builtin_amdgcn_mfma_f32_16x16x32_f16(a, b, acc, 0, 0, 0);
            }
#pragma unroll
            for (int r = 0; r < 4; ++r)
                Dlds[p][(drow0 + r) * 17 + dcol] = acc[r];
        }
        __syncthreads();
        if (tid < 64) {
            if (doC1) {
                int bb = tid & 15, up = tid >> 4;
                unsigned pk = 0;
#pragma unroll
                for (int j = 0; j < 2; ++j) {
                    int ul = up * 2 + j;
                    float gi = G1S[(0 * 8 + ul) * 16 + bb] + Dlds[0][(0 * 8 + ul) * 17 + bb];
                    float gf = G1S[(1 * 8 + ul) * 16 + bb] + Dlds[0][(1 * 8 + ul) * 17 + bb];
                    float gg = G1S[(2 * 8 + ul) * 16 + bb] + Dlds[0][(2 * 8 + ul) * 17 + bb];
                    float go = G1S[(3 * 8 + ul) * 16 + bb] + Dlds[0][(3 * 8 + ul) * 17 + bb];
                    float cn = fsig(gf) * C1S[bb * 8 + ul] + fsig(gi) * ftanhf(gg);
                    C1S[bb * 8 + ul] = cn;
                    _Float16 hv = (_Float16)(fsig(go) * ftanhf(cn));
                    pk |= (unsigned)__builtin_bit_cast(ushort_t, hv) << (16 * j);
                }
                unsigned* dst = (unsigned*)h1h;
                __hip_atomic_store(&dst[(size_t)((k + 1) * 16 + bb) * 256 + bk * 4 + up],
                                   pk, __ATOMIC_RELAXED, __HIP_MEMORY_SCOPE_AGENT);
            }
        } else if (tid < 128) {
            if (doC2) {
                int t2 = tid - 64;
                int bb = t2 & 15, up = t2 >> 4;
                unsigned pk = 0;
#pragma unroll
                for (int j = 0; j < 2; ++j) {
                    int ul = up * 2 + j;
                    float gi = bs[0][j] + Dlds[1][(0 * 8 + ul) * 17 + bb] + Dlds[2][(0 * 8 + ul) * 17 + bb];
                    float gf = bs[1][j] + Dlds[1][(1 * 8 + ul) * 17 + bb] + Dlds[2][(1 * 8 + ul) * 17 + bb];
                    float gg = bs[2][j] + Dlds[1][(2 * 8 + ul) * 17 + bb] + Dlds[2][(2 * 8 + ul) * 17 + bb];
                    float go = bs[3][j] + Dlds[1][(3 * 8 + ul) * 17 + bb] + Dlds[2][(3 * 8 + ul) * 17 + bb];
                    float cn = fsig(gf) * C2S[bb * 8 + ul] + fsig(gi) * ftanhf(gg);
                    C2S[bb * 8 + ul] = cn;
                    _Float16 hv = (_Float16)(fsig(go) * ftanhf(cn));
                    pk |= (unsigned)__builtin_bit_cast(ushort_t, hv) << (16 * j);
                }
                unsigned* dst = (unsigned*)h2h;
                __hip_atomic_store(&dst[(size_t)(k * 16 + bb) * 256 + bk * 4 + up],
                                   pk, __ATOMIC_RELAXED, __HIP_MEMORY_SCOPE_AGENT);
            }
        }
        gbar4(barflags, (unsigned)(k + 1));
    }
}

// ---------------------------------------------------------------------------
// Attention; glimpse reads Vh (f16) when available, else V (f32)
// ---------------------------------------------------------------------------
__launch_bounds__(256)
__global__ void attention_k(const _Float16* __restrict__ conv2Vh, const float* __restrict__ hproj,
                            const float* __restrict__ V, const _Float16* __restrict__ Vh,
                            const float* __restrict__ w3, const float* __restrict__ b3,
                            float* __restrict__ attw_out, float* __restrict__ glimpse)
{
    const int r = blockIdx.x;
    const int to = r >> 4, b = r & 15;
    const int tid = threadIdx.x;
    const _Float16* cb = conv2Vh + (size_t)b * 512 * 256;
    const float* hp = hproj + (size_t)r * 512;
    __shared__ float red[256];
    float acc = 0.f;
#pragma unroll 4
    for (int d = 0; d < 512; ++d) {
        float x = (float)cb[(size_t)d * 256 + tid] + hp[d];
        acc = fmaf(w3[d], ftanhf(x), acc);
    }
    float logit = acc + b3[0];
    red[tid] = logit; __syncthreads();
    for (int s = 128; s > 0; s >>= 1) { if (tid < s) red[tid] = fmaxf(red[tid], red[tid + s]); __syncthreads(); }
    float mx = red[0]; __syncthreads();
    float e = __expf(logit - mx);
    red[tid] = e; __syncthreads();
    for (int s = 128; s > 0; s >>= 1) { if (tid < s) red[tid] += red[tid + s]; __syncthreads(); }
    float aw = e / red[0];
    __syncthreads();
    attw_out[(size_t)b * 10240 + (size_t)to * 256 + tid] = aw;
    red[tid] = aw; __syncthreads();
    if (Vh) {
        const _Float16* Vb = Vh + (size_t)b * 512 * 256;
#pragma unroll
        for (int dl = 0; dl < 2; ++dl) {
            int d = tid + dl * 256;
            float g = 0.f;
            for (int p8 = 0; p8 < 256; p8 += 8) {
                f16x8 vv = *(const f16x8*)(Vb + (size_t)d * 256 + p8);
#pragma unroll
                for (int j = 0; j < 8; ++j)
                    g = fmaf((float)vv[j], red[p8 + j], g);
            }
            glimpse[(size_t)r * 512 + d] = g;
        }
    } else {
        const float* Vb = V + (size_t)b * 512 * 256;
#pragma unroll
        for (int dl = 0; dl < 2; ++dl) {
            int d = tid + dl * 256;
            float g = 0.f;
            for (int p4 = 0; p4 < 256; p4 += 4) {
                float4 vv = *(const float4*)(Vb + (size_t)d * 256 + p4);
                g = fmaf(vv.x, red[p4], g);     g = fmaf(vv.y, red[p4 + 1], g);
                g = fmaf(vv.z, red[p4 + 2], g); g = fmaf(vv.w, red[p4 + 3], g);
            }
            glimpse[(size_t)r * 512 + d] = g;
        }
    }
}

// In-place log_softmax over rows of 7000. grid = 640
__launch_bounds__(256)
__global__ void logsoftmax_k(float* __restrict__ out)
{
    int r = blockIdx.x;
    int b = r & 15, to = r >> 4;
    float* row = out + (size_t)b * 280000 + (size_t)to * 7000;
    __shared__ float buf[7000];
    __shared__ float red[256];
    int tid = threadIdx.x;
    float mx = -1e30f;
    for (int i = tid; i < 7000; i += 256) { float v = row[i]; buf[i] = v; mx = fmaxf(mx, v); }
    red[tid] = mx; __syncthreads();
    for (int s = 128; s > 0; s >>= 1) { if (tid < s) red[tid] = fmaxf(red[tid], red[tid + s]); __syncthreads(); }
    mx = red[0]; __syncthreads();
    float sm = 0.f;
    for (int i = tid; i < 7000; i += 256) sm += __expf(buf[i] - mx);
    red[tid] = sm; __syncthreads();
    for (int s = 128; s > 0; s >>= 1) { if (tid < s) red[tid] += red[tid + s]; __syncthreads(); }
    float lse = mx + __logf(red[0]);
    for (int i = tid; i < 7000; i += 256) row[i] = buf[i] - lse;
}

// ---------------------------------------------------------------------------
extern "C" void kernel_launch(void* const* d_in, const int* in_sizes, int n_in,
                              void* d_out, int out_size, void* d_ws, size_t ws_size,
                              hipStream_t stream)
{
    const float* hw      = (const float*)d_in[0];
    const float* y       = (const float*)d_in[1];
    const float* V       = (const float*)d_in[2];
    const float* w_lin1  = (const float*)d_in[3];
    const float* b_lin1  = (const float*)d_in[4];
    const float* W_ih    = (const float*)d_in[5];
    const float* b_ih    = (const float*)d_in[6];
    const float* W_hh    = (const float*)d_in[7];
    const float* b_hh    = (const float*)d_in[8];
    const float* w_conv1 = (const float*)d_in[9];
    const float* b_conv1 = (const float*)d_in[10];
    const float* w_conv2 = (const float*)d_in[11];
    const float* b_conv2 = (const float*)d_in[12];
    const float* w_conv3 = (const float*)d_in[13];
    const float* b_conv3 = (const float*)d_in[14];
    const float* w_lin2  = (const float*)d_in[15];
    const float* b_lin2  = (const float*)d_in[16];
    float* out = (float*)d_out;

    float* ws = (float*)d_ws;
    // persistent layout (float offsets)
    float* xs_tf   = ws + 0;                         // 319,488 (fallback accum)
    unsigned* barflags = (unsigned*)(ws + 319488);   // 4,096
    float* xs      = ws + 323584;                    // 335,872
    float* g1x     = ws + 659456;                    // 1,343,488
    ushort_t* conv2Vh = (ushort_t*)(ws + 2002944);   // 1,048,576 f
    ushort_t* wconv   = (ushort_t*)(ws + 3051520);   // 1,179,648 f
    float* hproj   = ws + 4231168;                   // 327,680
    float* glimpse = ws + 4558848;                   // 327,680
    ushort_t* h1h  = (ushort_t*)(ws + 5541888);      // 172,032 f
    ushort_t* h2h  = (ushort_t*)(ws + 5713920);      // 172,032 f
    float* w2lh_f  = ws + 5885952;                   // 3,584,000 -> 9,469,952
    ushort_t* w2lh = (ushort_t*)w2lh_f;
    ushort_t* Vh   = (ushort_t*)(ws + 9469952);      // 524,288 -> 9,994,240
    // transient aliases
    ushort_t* yh   = (ushort_t*)(ws + 659456);       // 2,196,480 f (dead after y-gemm)
    ushort_t* wlh  = (ushort_t*)(ws + 2855936);      // 1,802,240 f (dead after y-gemm)
    float* slabs   = w2lh_f;                         // 8 x 319,488 = 2,555,904 (dead after build_xs)
    ushort_t* wprep = (ushort_t*)(ws + 4231168);     // 1,048,576 f (hproj..pre-h1h; dead after lstm)
    const bool big = ws_size >= (size_t)9994240 * sizeof(float);

    // zero: xs_tf (fallback accum) + barflags; h1h/h2h slot 0
    hipMemsetAsync(ws, 0, (size_t)323584 * sizeof(float), stream);
    hipMemsetAsync(h1h, 0, 16384, stream);
    hipMemsetAsync(h2h, 0, 16384, stream);

    // y + w_lin1 -> f16 (one launch; yh/wlh contiguous)
    cvt_yw<<<1136, 256, 0, stream>>>(y, w_lin1, yh);

    // xs_tf/slabs = y @ w_lin1^T (624x512, K=7040, split-K=8)
    if (big) {
        gemm16<<<dim3(10, 8, 8), 256, 0, stream>>>(nullptr, (const _Float16*)yh,
                                                   nullptr, (const _Float16*)wlh,
                                                   slabs, 624, 512, 7040, 7040, 7040, 512,
                                                   nullptr, nullptr, 0, 8, 1, 319488, 0);
        build_xs<<<656, 256, 0, stream>>>(hw, slabs, w_lin1, b_lin1, xs, 8);
        cvt16<<<1024, 256, 0, stream>>>(w_lin2, w2lh, 7000, 1024, 1024);  // overwrites slabs
    } else {
        gemm16<<<dim3(10, 8, 8), 256, 0, stream>>>(nullptr, (const _Float16*)yh,
                                                   nullptr, (const _Float16*)wlh,
                                                   xs_tf, 624, 512, 7040, 7040, 7040, 512,
                                                   nullptr, nullptr, 0, 8, 0, 0, 0);
        build_xs<<<656, 256, 0, stream>>>(hw, xs_tf, w_lin1, b_lin1, xs, 1);
    }

    // weight preps (conv + lstm fused)
    wprep_all<<<8704, 64, 0, stream>>>(w_conv2, wconv, W_ih, W_hh, wprep);

    // g1x = xs @ W_ih^T + b_ih + b_hh
    gemm16<<<dim3(11, 32), 256, 0, stream>>>(xs, nullptr, W_ih, nullptr,
                                             g1x, 656, 2048, 512, 512, 512, 2048,
                                             b_ih, b_hh, 0, 1, 0, 0, 0);
    // conv (+ Vh f16 persist when big)
    conv_mfma<<<256, 256, 0, stream>>>(V, wconv, b_conv2, conv2Vh, big ? Vh : nullptr);

    // sequential recurrence
    void* args[] = {(void*)&g1x, (void*)&wprep, (void*)&b_ih, (void*)&b_hh,
                    (void*)&h1h, (void*)&h2h, (void*)&barflags};
    hipLaunchCooperativeKernel((void*)lstm_rec, dim3(LSTM_NB), dim3(512), args, 0, stream);

    // hproj = h2[1..40] @ w1^T + b_conv1
    gemm16<<<dim3(10, 8), 256, 0, stream>>>(nullptr, (const _Float16*)h2h + 32 * 512,
                                            w_conv1, nullptr,
                                            hproj, 640, 512, 512, 512, 512, 512,
                                            b_conv1, nullptr, 0, 1, 0, 0, 0);
    attention_k<<<640, 256, 0, stream>>>((const _Float16*)conv2Vh, hproj, V,
                                         big ? (const _Float16*)Vh : nullptr,
                                         w_conv3, b_conv3, out + 4480000, glimpse);
    // logits: A = virtual [h2 | glimpse]; B = w_lin2 (f16 if big)
    if (big)
        gemm16<<<dim3(10, 110), 256, 0, stream>>>(glimpse, (const _Float16*)h2h + 32 * 512,
                                                  nullptr, (const _Float16*)w2lh,
                                                  out, 640, 7000, 1024, 1024, 1024, 7000,
                                                  b_lin2, nullptr, 2, 1, 0, 0, 1);
    else
        gemm16<<<dim3(10, 110), 256, 0, stream>>>(glimpse, (const _Float16*)h2h + 32 * 512,
                                                  w_lin2, nullptr,
                                                  out, 640, 7000, 1024, 1024, 1024, 7000,
                                                  b_lin2, nullptr, 2, 1, 0, 0, 1);
    logsoftmax_k<<<640, 256, 0, stream>>>(out);
}